// Round 3
// baseline (4313.770 us; speedup 1.0000x reference)
//
#include <hip/hip_runtime.h>
#include <math.h>

#define NB  256
#define T   1024
#define DIN 64
#define H   128
#define G4  512

typedef __attribute__((ext_vector_type(4))) float    f32x4;
typedef __attribute__((ext_vector_type(8))) _Float16 f16x8;

#define DPPQ(v, CTRL) __int_as_float(__builtin_amdgcn_update_dpp(0, __float_as_int(v), (CTRL), 0xf, 0xf, true))
#define MFMA16(A, B, C) __builtin_amdgcn_mfma_f32_16x16x32_f16((A), (B), (C), 0, 0, 0)

__device__ __forceinline__ float tanhf_(float x) { return 2.0f / (1.0f + __expf(-2.0f * x)) - 1.0f; }

__device__ __forceinline__ f16x8 cvt8(const float* p) {
    float4 v0 = *(const float4*)p;
    float4 v1 = *(const float4*)(p + 4);
    return (f16x8){(_Float16)v0.x, (_Float16)v0.y, (_Float16)v0.z, (_Float16)v0.w,
                   (_Float16)v1.x, (_Float16)v1.y, (_Float16)v1.z, (_Float16)v1.w};
}

// ---------------------------------------------------------------------------
// Fully-fused 2-layer LSTM + FC. grid = NB blocks (1 batch each), 512 thr.
// Per iteration s (skewed pipeline, all three jobs independent within s):
//   l0: h0(s)       = LSTM(whh0 @ h0(s-1) + wih0 @ x(s) + b0)        [s < T]
//   m1: xg1p(s-1)   = wih1 @ h0(s-1)                                  [s <= T]
//   l1: h1(s-2)     = LSTM(xg1p(s-2) + whh1 @ h1(s-3) + b1)          [s >= 2]
// Lane t owns gate' column n == t (gate = t&3, hu = t>>2); MFMA matvec with
// h broadcast over M rows; acc N-tile selected by lane>>4 (3 cndmask).
// Own-gate nonlinearity then quad-DPP broadcast (round-1-verified layout).
// All weight fragments f16 register-resident (~224 VGPR); one barrier/step;
// no global traffic in the loop except a 1-dword/lane x prefetch by wave 0.
// ---------------------------------------------------------------------------
__global__ __launch_bounds__(512, 1)
void lstm_fused(const float* __restrict__ x,   const float* __restrict__ h0g,
                const float* __restrict__ wih0, const float* __restrict__ whh0, const float* __restrict__ b0,
                const float* __restrict__ wih1, const float* __restrict__ whh1, const float* __restrict__ b1,
                const float* __restrict__ fcw,  const float* __restrict__ fcb,
                float* __restrict__ out)
{
    __shared__ _Float16 __align__(16) h0buf[2][H];
    __shared__ _Float16 __align__(16) h1buf[2][H];
    __shared__ _Float16 __align__(16) xbuf[2][DIN];
    __shared__ float xg1p[2][G4];
    __shared__ float lds_r[H];

    const int b    = blockIdx.x;
    const int t    = threadIdx.x;
    const int lane = t & 63;
    const int v    = t >> 6;
    const int l15  = lane & 15;
    const int q    = lane >> 4;

    // ---- weight fragments (f16, register-resident) ----
    // B-frag for N-tile j: col n = 64v + 16j + l15; k = 32kt + q*8 + jj
    f16x8 whh0f[4][4], wih0f[4][2], wih1f[4][4], whh1f[4][4];
    #pragma unroll
    for (int j = 0; j < 4; ++j) {
        const int n  = 64 * v + 16 * j + l15;
        const int pn = (n & 3) * 128 + (n >> 2);      // gate' -> original row
        const float* r0 = whh0 + (size_t)pn * H;
        const float* ri = wih1 + (size_t)pn * H;
        const float* r1 = whh1 + (size_t)pn * H;
        const float* rx = wih0 + (size_t)pn * DIN;
        #pragma unroll
        for (int kt = 0; kt < 4; ++kt) {
            const int base = 32 * kt + q * 8;
            whh0f[j][kt] = cvt8(r0 + base);
            wih1f[j][kt] = cvt8(ri + base);
            whh1f[j][kt] = cvt8(r1 + base);
        }
        #pragma unroll
        for (int k2 = 0; k2 < 2; ++k2)
            wih0f[j][k2] = cvt8(rx + 32 * k2 + q * 8);
    }

    const float b0j = b0[(t & 3) * 128 + (t >> 2)];
    const float b1j = b1[(t & 3) * 128 + (t >> 2)];

    // per-lane nonlinearity constants (gate 2 = cell/tanh gate)
    const bool  isg = (t & 3) == 2;
    const float nsc = isg ? -2.0f : -1.0f;
    const float va  = isg ?  2.0f :  1.0f;
    const float vb  = isg ? -1.0f :  0.0f;
    const bool  s4  = (lane & 16) != 0;
    const bool  s5  = (lane & 32) != 0;

    // ---- init ----
    if (t < H) {
        h0buf[0][t] = (_Float16)h0g[(size_t)b * H + t];                 // h0(-1)
        h1buf[1][t] = (_Float16)h0g[(size_t)(NB + b) * H + t];          // h1(-1)
    }
    float xA = 0.0f, xB = 0.0f;
    if (t < DIN) {
        const float* xb = x + (size_t)b * T * DIN;
        xbuf[0][t] = (_Float16)xb[t];                                   // x(0)
        xA = xb[DIN + t];                                               // x(1)
        xB = xb[2 * DIN + t];                                           // x(2)
    }
    float c0 = 0.0f, c1 = 0.0f, h1last = 0.0f;
    __syncthreads();

    const f32x4 z = (f32x4){0.f, 0.f, 0.f, 0.f};

    for (int s = 0; s <= T + 1; ++s) {
        const int  p   = s & 1;
        const bool do0 = (s < T);
        const bool dom = (s <= T);
        const bool do1 = (s >= 2);

        // x prefetch / staging (wave 0): write x(s+1), load x(s+3)
        if (t < DIN) {
            xbuf[p ^ 1][t] = (_Float16)xA;
            xA = xB;
            int sn = s + 3; if (sn > T - 1) sn = T - 1;
            xB = x[(size_t)b * T * DIN + (size_t)sn * DIN + t];
        }

        // ---- A-fragment LDS reads (broadcast) ----
        f16x8 af0[4], afx[2], af1[4];
        if (dom) {
            #pragma unroll
            for (int kt = 0; kt < 4; ++kt)
                af0[kt] = *(const f16x8*)(&h0buf[p][0] + 32 * kt + q * 8);
        }
        if (do0) {
            afx[0] = *(const f16x8*)(&xbuf[p][0] + q * 8);
            afx[1] = *(const f16x8*)(&xbuf[p][0] + 32 + q * 8);
        }
        if (do1) {
            #pragma unroll
            for (int kt = 0; kt < 4; ++kt)
                af1[kt] = *(const f16x8*)(&h1buf[p ^ 1][0] + 32 * kt + q * 8);
        }

        // ---- l0: h0(s) ----
        if (do0) {
            f32x4 a0 = z, a1 = z, a2 = z, a3 = z;
            #pragma unroll
            for (int kt = 0; kt < 4; ++kt) {
                a0 = MFMA16(af0[kt], whh0f[0][kt], a0);
                a1 = MFMA16(af0[kt], whh0f[1][kt], a1);
                a2 = MFMA16(af0[kt], whh0f[2][kt], a2);
                a3 = MFMA16(af0[kt], whh0f[3][kt], a3);
            }
            #pragma unroll
            for (int k2 = 0; k2 < 2; ++k2) {
                a0 = MFMA16(afx[k2], wih0f[0][k2], a0);
                a1 = MFMA16(afx[k2], wih0f[1][k2], a1);
                a2 = MFMA16(afx[k2], wih0f[2][k2], a2);
                a3 = MFMA16(afx[k2], wih0f[3][k2], a3);
            }
            float glo = s4 ? a1[0] : a0[0];
            float ghi = s4 ? a3[0] : a2[0];
            float g   = (s5 ? ghi : glo) + b0j;

            float u  = 1.0f / (1.0f + __expf(nsc * g));
            float vl = fmaf(u, va, vb);
            float ni = DPPQ(vl, 0x00);
            float nf = DPPQ(vl, 0x55);
            float ng = DPPQ(vl, 0xAA);
            float no = DPPQ(vl, 0xFF);
            c0 = nf * c0 + ni * ng;
            float h0v = no * tanhf_(c0);
            if ((t & 3) == 0) h0buf[p ^ 1][t >> 2] = (_Float16)h0v;
        }

        // ---- m1: xg1p(s-1) = wih1 @ h0(s-1) ----
        if (dom) {
            f32x4 a0 = z, a1 = z, a2 = z, a3 = z;
            #pragma unroll
            for (int kt = 0; kt < 4; ++kt) {
                a0 = MFMA16(af0[kt], wih1f[0][kt], a0);
                a1 = MFMA16(af0[kt], wih1f[1][kt], a1);
                a2 = MFMA16(af0[kt], wih1f[2][kt], a2);
                a3 = MFMA16(af0[kt], wih1f[3][kt], a3);
            }
            float glo = s4 ? a1[0] : a0[0];
            float ghi = s4 ? a3[0] : a2[0];
            xg1p[p][t] = s5 ? ghi : glo;
        }

        // ---- l1: h1(s-2) ----
        if (do1) {
            f32x4 a0 = z, a1 = z, a2 = z, a3 = z;
            #pragma unroll
            for (int kt = 0; kt < 4; ++kt) {
                a0 = MFMA16(af1[kt], whh1f[0][kt], a0);
                a1 = MFMA16(af1[kt], whh1f[1][kt], a1);
                a2 = MFMA16(af1[kt], whh1f[2][kt], a2);
                a3 = MFMA16(af1[kt], whh1f[3][kt], a3);
            }
            float glo = s4 ? a1[0] : a0[0];
            float ghi = s4 ? a3[0] : a2[0];
            float g   = (s5 ? ghi : glo) + xg1p[p ^ 1][t] + b1j;

            float u  = 1.0f / (1.0f + __expf(nsc * g));
            float vl = fmaf(u, va, vb);
            float ni = DPPQ(vl, 0x00);
            float nf = DPPQ(vl, 0x55);
            float ng = DPPQ(vl, 0xAA);
            float no = DPPQ(vl, 0xFF);
            c1 = nf * c1 + ni * ng;
            float h1v = no * tanhf_(c1);
            h1last = h1v;
            if ((t & 3) == 0) h1buf[p][t >> 2] = (_Float16)h1v;
        }

        __syncthreads();
    }

    // ---- FC epilogue: out[b] = h1(T-1) . fcw + fcb ----
    if ((t & 3) == 0) lds_r[t >> 2] = h1last * fcw[t >> 2];
    __syncthreads();
    if (t == 0) {
        float s = fcb[0];
        for (int k = 0; k < H; ++k) s += lds_r[k];
        out[b] = s;
    }
}

extern "C" void kernel_launch(void* const* d_in, const int* in_sizes, int n_in,
                              void* d_out, int out_size, void* d_ws, size_t ws_size,
                              hipStream_t stream)
{
    const float* x    = (const float*)d_in[0];
    const float* h0   = (const float*)d_in[1];
    const float* wih0 = (const float*)d_in[2];
    const float* whh0 = (const float*)d_in[3];
    const float* b0   = (const float*)d_in[4];
    const float* wih1 = (const float*)d_in[5];
    const float* whh1 = (const float*)d_in[6];
    const float* b1   = (const float*)d_in[7];
    const float* fcw  = (const float*)d_in[8];
    const float* fcb  = (const float*)d_in[9];
    float* out = (float*)d_out;

    lstm_fused<<<NB, 512, 0, stream>>>(x, h0, wih0, whh0, b0,
                                       wih1, whh1, b1, fcw, fcb, out);
}

// Round 4
// 2096.792 us; speedup vs baseline: 2.0573x; 2.0573x over previous
//
#include <hip/hip_runtime.h>
#include <math.h>

#define NB  256
#define T   1024
#define DIN 64
#define H   128
#define G4  512

typedef __attribute__((ext_vector_type(4))) float    f32x4;
typedef __attribute__((ext_vector_type(8))) _Float16 f16x8;

#define DPPQ(v, CTRL) __int_as_float(__builtin_amdgcn_update_dpp(0, __float_as_int(v), (CTRL), 0xf, 0xf, true))
#define MFMA16(A, B, C) __builtin_amdgcn_mfma_f32_16x16x32_f16((A), (B), (C), 0, 0, 0)

__device__ __forceinline__ float tanhf_(float x) { return 2.0f / (1.0f + __expf(-2.0f * x)) - 1.0f; }

__device__ __forceinline__ f16x8 cvt8(const float* p) {
    float4 v0 = *(const float4*)p;
    float4 v1 = *(const float4*)(p + 4);
    return (f16x8){(_Float16)v0.x, (_Float16)v0.y, (_Float16)v0.z, (_Float16)v0.w,
                   (_Float16)v1.x, (_Float16)v1.y, (_Float16)v1.z, (_Float16)v1.w};
}

// ---------------------------------------------------------------------------
// Pre-pass GEMM: xg0[r][n'] = sum_k x[r][k] * wih0[pn(n')][k]   (f16 MFMA)
// r = b*T+s (contiguous), n' = gate'-order column, pn = (n&3)*128 + (n>>2).
// Tile 128x128, K=64 single pass. grid = (NB*T/128) * 4.
// ---------------------------------------------------------------------------
__global__ __launch_bounds__(256, 2)
void gemm_xg0(const float* __restrict__ x, const float* __restrict__ wih0,
              _Float16* __restrict__ xg0)
{
    __shared__ _Float16 __align__(16) sA[128][72];
    __shared__ _Float16 __align__(16) sW[128][72];

    const int bid = blockIdx.x;
    const int mb = bid >> 2, nb = bid & 3;
    const int m0 = mb << 7, n0 = nb << 7;

    const int j = threadIdx.x;
    const int lane = j & 63, wv = j >> 6;
    const int wm = wv >> 1, wn = wv & 1;
    const int q = lane >> 4, n16 = lane & 15;

    #pragma unroll
    for (int it = 0; it < 8; ++it) {
        int idx = j + it * 256;
        int r = idx >> 4, kc = (idx & 15) << 2;
        float4 va = *(const float4*)(x + (size_t)(m0 + r) * DIN + kc);
        sA[r][kc + 0] = (_Float16)va.x; sA[r][kc + 1] = (_Float16)va.y;
        sA[r][kc + 2] = (_Float16)va.z; sA[r][kc + 3] = (_Float16)va.w;
        int n = n0 + r, pn = (n & 3) * 128 + (n >> 2);
        float4 vw = *(const float4*)(wih0 + (size_t)pn * DIN + kc);
        sW[r][kc + 0] = (_Float16)vw.x; sW[r][kc + 1] = (_Float16)vw.y;
        sW[r][kc + 2] = (_Float16)vw.z; sW[r][kc + 3] = (_Float16)vw.w;
    }
    __syncthreads();

    f32x4 acc[4][4];
    #pragma unroll
    for (int a = 0; a < 4; ++a)
        #pragma unroll
        for (int bq = 0; bq < 4; ++bq) acc[a][bq] = (f32x4){0.f, 0.f, 0.f, 0.f};

    #pragma unroll
    for (int kh = 0; kh < 2; ++kh) {
        const int kk = kh * 32 + q * 8;
        f16x8 a[4], bfr[4];
        #pragma unroll
        for (int mt = 0; mt < 4; ++mt)
            a[mt] = *(const f16x8*)&sA[wm * 64 + mt * 16 + n16][kk];
        #pragma unroll
        for (int nt = 0; nt < 4; ++nt)
            bfr[nt] = *(const f16x8*)&sW[wn * 64 + nt * 16 + n16][kk];
        #pragma unroll
        for (int nt = 0; nt < 4; ++nt)
            #pragma unroll
            for (int mt = 0; mt < 4; ++mt)
                acc[mt][nt] = MFMA16(a[mt], bfr[nt], acc[mt][nt]);
    }

    #pragma unroll
    for (int mt = 0; mt < 4; ++mt)
        #pragma unroll
        for (int nt = 0; nt < 4; ++nt) {
            int row = m0 + wm * 64 + mt * 16 + q * 4;
            int col = n0 + wn * 64 + nt * 16 + n16;
            #pragma unroll
            for (int r = 0; r < 4; ++r)
                xg0[(size_t)(row + r) * G4 + col] = (_Float16)acc[mt][nt][r];
        }
}

// ---------------------------------------------------------------------------
// Fully-fused 2-layer LSTM + FC. grid = NB blocks (1 batch/CU), 256 thr
// (4 waves = 1 wave/SIMD -> VGPR cap 512). Lane t owns gate' cols t and
// t+256 (same gate type, hidden units hu and hu+64). Register-resident f16
// weight fragments: whh0 + wih1 + whh1 = 384 VGPR. W_ih0*x precomputed
// into xg0 (f16) by gemm_xg0. Skewed pipeline per iteration s:
//   l0: h0(s) [s<T];  m1: xg1p(s-1)=wih1@h0(s-1) [s<=T];  l1: h1(s-2) [s>=2]
// ONE barrier per iteration; only global traffic in loop = 2 f16/lane xg0.
// ---------------------------------------------------------------------------
__global__ __launch_bounds__(256, 1)
void lstm_fused(const _Float16* __restrict__ xg0, const float* __restrict__ h0g,
                const float* __restrict__ whh0, const float* __restrict__ b0,
                const float* __restrict__ wih1, const float* __restrict__ whh1,
                const float* __restrict__ b1,
                const float* __restrict__ fcw, const float* __restrict__ fcb,
                float* __restrict__ out)
{
    __shared__ _Float16 __align__(16) h0buf[2][H];
    __shared__ _Float16 __align__(16) h1buf[2][H];
    __shared__ float xg1p[2][G4];
    __shared__ float lds_r[H];

    const int b    = blockIdx.x;
    const int t    = threadIdx.x;        // 0..255
    const int lane = t & 63;
    const int v    = t >> 6;             // wave 0..3
    const int l15  = lane & 15;
    const int q    = lane >> 4;

    // ---- weight fragments (f16, register-resident): halves hx=0 (cols
    // 64v+16j+l15) and hx=1 (+256). B-frag k = 32kt + q*8 + jj.
    f16x8 w0f[2][4][4], wi1f[2][4][4], w1f[2][4][4];
    #pragma unroll
    for (int hx = 0; hx < 2; ++hx)
        #pragma unroll
        for (int jj = 0; jj < 4; ++jj) {
            const int n  = 256 * hx + 64 * v + 16 * jj + l15;
            const int pn = (n & 3) * 128 + (n >> 2);     // gate' -> original row
            const float* r0 = whh0 + (size_t)pn * H;
            const float* ri = wih1 + (size_t)pn * H;
            const float* r1 = whh1 + (size_t)pn * H;
            #pragma unroll
            for (int kt = 0; kt < 4; ++kt) {
                const int base = 32 * kt + q * 8;
                w0f[hx][jj][kt]  = cvt8(r0 + base);
                wi1f[hx][jj][kt] = cvt8(ri + base);
                w1f[hx][jj][kt]  = cvt8(r1 + base);
            }
        }

    const int g  = t & 3;                // own gate (same for both cols)
    const int hu = t >> 2;               // hidden unit of col t (col t+256 -> hu+64)
    const float b0A = b0[g * 128 + hu], b0B = b0[g * 128 + hu + 64];
    const float b1A = b1[g * 128 + hu], b1B = b1[g * 128 + hu + 64];

    const bool  isg = (g == 2);
    const float nsc = isg ? -2.0f : -1.0f;
    const float va  = isg ?  2.0f :  1.0f;
    const float vb  = isg ? -1.0f :  0.0f;
    const bool  s4  = (lane & 16) != 0;
    const bool  s5  = (lane & 32) != 0;

    if (t < H) {
        h0buf[0][t] = (_Float16)h0g[(size_t)b * H + t];          // h0(-1)
        h1buf[1][t] = (_Float16)h0g[(size_t)(NB + b) * H + t];   // h1(-1)
    }
    float cA0 = 0.f, cB0 = 0.f, cA1 = 0.f, cB1 = 0.f;
    float h1A = 0.f, h1B = 0.f;

    const _Float16* xb = xg0 + (size_t)b * T * G4;
    float xA0 = (float)xb[t],      xB0 = (float)xb[t + 256];
    float xA1 = (float)xb[G4 + t], xB1 = (float)xb[G4 + t + 256];
    __syncthreads();

    const f32x4 z = (f32x4){0.f, 0.f, 0.f, 0.f};

    for (int s = 0; s <= T + 1; ++s) {
        const int  p   = s & 1;
        const bool do0 = (s < T);
        const bool dom = (s <= T);
        const bool do1 = (s >= 2);

        f16x8 af0[4];
        if (dom) {
            #pragma unroll
            for (int kt = 0; kt < 4; ++kt)
                af0[kt] = *(const f16x8*)(&h0buf[p][0] + 32 * kt + q * 8);
        }

        // ---- l0: h0(s) ----
        if (do0) {
            f32x4 aA0 = z, aA1 = z, aA2 = z, aA3 = z;
            f32x4 aB0 = z, aB1 = z, aB2 = z, aB3 = z;
            #pragma unroll
            for (int kt = 0; kt < 4; ++kt) {
                aA0 = MFMA16(af0[kt], w0f[0][0][kt], aA0);
                aA1 = MFMA16(af0[kt], w0f[0][1][kt], aA1);
                aA2 = MFMA16(af0[kt], w0f[0][2][kt], aA2);
                aA3 = MFMA16(af0[kt], w0f[0][3][kt], aA3);
                aB0 = MFMA16(af0[kt], w0f[1][0][kt], aB0);
                aB1 = MFMA16(af0[kt], w0f[1][1][kt], aB1);
                aB2 = MFMA16(af0[kt], w0f[1][2][kt], aB2);
                aB3 = MFMA16(af0[kt], w0f[1][3][kt], aB3);
            }
            float gA = (s5 ? (s4 ? aA3[0] : aA2[0]) : (s4 ? aA1[0] : aA0[0])) + xA0 + b0A;
            float gB = (s5 ? (s4 ? aB3[0] : aB2[0]) : (s4 ? aB1[0] : aB0[0])) + xB0 + b0B;

            xA0 = xA1; xB0 = xB1;
            int sn = (s + 2 < T) ? (s + 2) : (T - 1);
            xA1 = (float)xb[(size_t)sn * G4 + t];
            xB1 = (float)xb[(size_t)sn * G4 + t + 256];

            float uA  = 1.0f / (1.0f + __expf(nsc * gA));
            float vlA = fmaf(uA, va, vb);
            float uB  = 1.0f / (1.0f + __expf(nsc * gB));
            float vlB = fmaf(uB, va, vb);

            float niA = DPPQ(vlA, 0x00), nfA = DPPQ(vlA, 0x55);
            float ngA = DPPQ(vlA, 0xAA), noA = DPPQ(vlA, 0xFF);
            float niB = DPPQ(vlB, 0x00), nfB = DPPQ(vlB, 0x55);
            float ngB = DPPQ(vlB, 0xAA), noB = DPPQ(vlB, 0xFF);

            cA0 = nfA * cA0 + niA * ngA;
            cB0 = nfB * cB0 + niB * ngB;
            float hA = noA * tanhf_(cA0);
            float hB = noB * tanhf_(cB0);
            if (g == 0) {
                h0buf[p ^ 1][hu]      = (_Float16)hA;
                h0buf[p ^ 1][hu + 64] = (_Float16)hB;
            }
        }

        // ---- m1: xg1p(s-1) = wih1 @ h0(s-1) ----
        if (dom) {
            f32x4 aA0 = z, aA1 = z, aA2 = z, aA3 = z;
            f32x4 aB0 = z, aB1 = z, aB2 = z, aB3 = z;
            #pragma unroll
            for (int kt = 0; kt < 4; ++kt) {
                aA0 = MFMA16(af0[kt], wi1f[0][0][kt], aA0);
                aA1 = MFMA16(af0[kt], wi1f[0][1][kt], aA1);
                aA2 = MFMA16(af0[kt], wi1f[0][2][kt], aA2);
                aA3 = MFMA16(af0[kt], wi1f[0][3][kt], aA3);
                aB0 = MFMA16(af0[kt], wi1f[1][0][kt], aB0);
                aB1 = MFMA16(af0[kt], wi1f[1][1][kt], aB1);
                aB2 = MFMA16(af0[kt], wi1f[1][2][kt], aB2);
                aB3 = MFMA16(af0[kt], wi1f[1][3][kt], aB3);
            }
            xg1p[p][t]       = s5 ? (s4 ? aA3[0] : aA2[0]) : (s4 ? aA1[0] : aA0[0]);
            xg1p[p][t + 256] = s5 ? (s4 ? aB3[0] : aB2[0]) : (s4 ? aB1[0] : aB0[0]);
        }

        // ---- l1: h1(s-2) ----
        if (do1) {
            f16x8 af1[4];
            #pragma unroll
            for (int kt = 0; kt < 4; ++kt)
                af1[kt] = *(const f16x8*)(&h1buf[p ^ 1][0] + 32 * kt + q * 8);

            f32x4 aA0 = z, aA1 = z, aA2 = z, aA3 = z;
            f32x4 aB0 = z, aB1 = z, aB2 = z, aB3 = z;
            #pragma unroll
            for (int kt = 0; kt < 4; ++kt) {
                aA0 = MFMA16(af1[kt], w1f[0][0][kt], aA0);
                aA1 = MFMA16(af1[kt], w1f[0][1][kt], aA1);
                aA2 = MFMA16(af1[kt], w1f[0][2][kt], aA2);
                aA3 = MFMA16(af1[kt], w1f[0][3][kt], aA3);
                aB0 = MFMA16(af1[kt], w1f[1][0][kt], aB0);
                aB1 = MFMA16(af1[kt], w1f[1][1][kt], aB1);
                aB2 = MFMA16(af1[kt], w1f[1][2][kt], aB2);
                aB3 = MFMA16(af1[kt], w1f[1][3][kt], aB3);
            }
            float gA = (s5 ? (s4 ? aA3[0] : aA2[0]) : (s4 ? aA1[0] : aA0[0]))
                       + xg1p[p ^ 1][t] + b1A;
            float gB = (s5 ? (s4 ? aB3[0] : aB2[0]) : (s4 ? aB1[0] : aB0[0]))
                       + xg1p[p ^ 1][t + 256] + b1B;

            float uA  = 1.0f / (1.0f + __expf(nsc * gA));
            float vlA = fmaf(uA, va, vb);
            float uB  = 1.0f / (1.0f + __expf(nsc * gB));
            float vlB = fmaf(uB, va, vb);

            float niA = DPPQ(vlA, 0x00), nfA = DPPQ(vlA, 0x55);
            float ngA = DPPQ(vlA, 0xAA), noA = DPPQ(vlA, 0xFF);
            float niB = DPPQ(vlB, 0x00), nfB = DPPQ(vlB, 0x55);
            float ngB = DPPQ(vlB, 0xAA), noB = DPPQ(vlB, 0xFF);

            cA1 = nfA * cA1 + niA * ngA;
            cB1 = nfB * cB1 + niB * ngB;
            h1A = noA * tanhf_(cA1);
            h1B = noB * tanhf_(cB1);
            if (g == 0) {
                h1buf[p][hu]      = (_Float16)h1A;
                h1buf[p][hu + 64] = (_Float16)h1B;
            }
        }

        __syncthreads();
    }

    // ---- FC epilogue: out[b] = h1(T-1) . fcw + fcb ----
    if (g == 0) {
        lds_r[hu]      = h1A * fcw[hu];
        lds_r[hu + 64] = h1B * fcw[hu + 64];
    }
    __syncthreads();
    if (t == 0) {
        float s = fcb[0];
        for (int k = 0; k < H; ++k) s += lds_r[k];
        out[b] = s;
    }
}

extern "C" void kernel_launch(void* const* d_in, const int* in_sizes, int n_in,
                              void* d_out, int out_size, void* d_ws, size_t ws_size,
                              hipStream_t stream)
{
    const float* x    = (const float*)d_in[0];
    const float* h0   = (const float*)d_in[1];
    const float* wih0 = (const float*)d_in[2];
    const float* whh0 = (const float*)d_in[3];
    const float* b0   = (const float*)d_in[4];
    const float* wih1 = (const float*)d_in[5];
    const float* whh1 = (const float*)d_in[6];
    const float* b1   = (const float*)d_in[7];
    const float* fcw  = (const float*)d_in[8];
    const float* fcb  = (const float*)d_in[9];
    float* out = (float*)d_out;

    _Float16* xg0 = (_Float16*)d_ws;   // [NB*T][512] f16 = 256 MiB

    gemm_xg0<<<(NB * T / 128) * 4, 256, 0, stream>>>(x, wih0, xg0);
    lstm_fused<<<NB, 256, 0, stream>>>(xg0, h0, whh0, b0, wih1, whh1, b1,
                                       fcw, fcb, out);
}

// Round 5
// 2073.151 us; speedup vs baseline: 2.0808x; 1.0114x over previous
//
#include <hip/hip_runtime.h>
#include <math.h>

#define NB  256
#define T   1024
#define DIN 64
#define H   128
#define G4  512
#define NBT (NB * T)

typedef __attribute__((ext_vector_type(4))) float    f32x4;
typedef __attribute__((ext_vector_type(8))) _Float16 f16x8;
typedef __attribute__((ext_vector_type(4))) _Float16 f16x4;

#define DPPQ(v, CTRL) __int_as_float(__builtin_amdgcn_update_dpp(0, __float_as_int(v), (CTRL), 0xf, 0xf, true))
#define MFMA16(A, B, C) __builtin_amdgcn_mfma_f32_16x16x32_f16((A), (B), (C), 0, 0, 0)

__device__ __forceinline__ float tanhf_(float x) { return 2.0f / (1.0f + __expf(-2.0f * x)) - 1.0f; }

__device__ __forceinline__ f16x8 cvt8(const float* p) {
    float4 v0 = *(const float4*)p;
    float4 v1 = *(const float4*)(p + 4);
    return (f16x8){(_Float16)v0.x, (_Float16)v0.y, (_Float16)v0.z, (_Float16)v0.w,
                   (_Float16)v1.x, (_Float16)v1.y, (_Float16)v1.z, (_Float16)v1.w};
}

// ---------------------------------------------------------------------------
// GEMM -> permuted-packed f16 xg:  O[row][pcol] = sum_k A[row][k] * W[pn(col)][k]
// pcol = (col>>6)*64 + (col&15)*4 + ((col>>4)&3)  (so the scan reads its 4
// per-lane cols as ONE 8-byte load). pn = (col&3)*128 + (col>>2) (gate' perm).
// One block owns a 128-row stripe and loops all 4 col-blocks -> its reads of
// A (which may alias O's tail region, K=128 path) all precede its writes.
// ---------------------------------------------------------------------------
template<int K, int AH>
__global__ __launch_bounds__(256, 2)
void gemm_pp(const void* __restrict__ A, long lda, const float* __restrict__ W,
             _Float16* __restrict__ O)
{
    __shared__ _Float16 __align__(16) sA[128][136];
    __shared__ _Float16 __align__(16) sW[128][72];

    const int m0 = blockIdx.x << 7;
    const int j = threadIdx.x;
    const int lane = j & 63, wv = j >> 6;
    const int wm = wv >> 1, wn = wv & 1;
    const int q = lane >> 4, n16 = lane & 15;

    if constexpr (AH) {
        const _Float16* Ah = (const _Float16*)A;
        #pragma unroll
        for (int it = 0; it < K / 16; ++it) {          // K=128 -> 8 iters
            int idx = j + it * 256;
            int r = idx >> 4, kc = (idx & 15) << 3;
            *(f16x8*)&sA[r][kc] = *(const f16x8*)(Ah + (size_t)(m0 + r) * lda + kc);
        }
    } else {
        const float* Af = (const float*)A;
        #pragma unroll
        for (int it = 0; it < K / 8; ++it) {           // K=64 -> 8 iters
            int idx = j + it * 256;
            int r = idx >> 4, kc = (idx & 15) << 2;
            float4 va = *(const float4*)(Af + (size_t)(m0 + r) * lda + kc);
            *(f16x4*)&sA[r][kc] = (f16x4){(_Float16)va.x, (_Float16)va.y,
                                          (_Float16)va.z, (_Float16)va.w};
        }
    }

    for (int nb = 0; nb < 4; ++nb) {
        f32x4 acc[4][4];
        #pragma unroll
        for (int a = 0; a < 4; ++a)
            #pragma unroll
            for (int bq = 0; bq < 4; ++bq) acc[a][bq] = (f32x4){0.f, 0.f, 0.f, 0.f};

        #pragma unroll
        for (int kp = 0; kp < K / 64; ++kp) {
            __syncthreads();
            #pragma unroll
            for (int it = 0; it < 8; ++it) {
                int idx = j + it * 256;
                int r = idx >> 4, kc = (idx & 15) << 2;
                int n = (nb << 7) + r, pn = (n & 3) * 128 + (n >> 2);
                float4 vw = *(const float4*)(W + (size_t)pn * K + kp * 64 + kc);
                *(f16x4*)&sW[r][kc] = (f16x4){(_Float16)vw.x, (_Float16)vw.y,
                                              (_Float16)vw.z, (_Float16)vw.w};
            }
            __syncthreads();
            #pragma unroll
            for (int kh = 0; kh < 2; ++kh) {
                const int kk = kh * 32 + q * 8;
                f16x8 a[4], bf[4];
                #pragma unroll
                for (int mt = 0; mt < 4; ++mt)
                    a[mt] = *(const f16x8*)&sA[wm * 64 + mt * 16 + n16][kp * 64 + kk];
                #pragma unroll
                for (int nt = 0; nt < 4; ++nt)
                    bf[nt] = *(const f16x8*)&sW[wn * 64 + nt * 16 + n16][kk];
                #pragma unroll
                for (int nt = 0; nt < 4; ++nt)
                    #pragma unroll
                    for (int mt = 0; mt < 4; ++mt)
                        acc[mt][nt] = MFMA16(a[mt], bf[nt], acc[mt][nt]);
            }
        }
        // epilogue: pack 4 col-block values -> one 8-byte store (permuted layout)
        #pragma unroll
        for (int mt = 0; mt < 4; ++mt)
            #pragma unroll
            for (int r = 0; r < 4; ++r) {
                int row = m0 + wm * 64 + mt * 16 + q * 4 + r;
                f16x4 pk = {(_Float16)acc[mt][0][r], (_Float16)acc[mt][1][r],
                            (_Float16)acc[mt][2][r], (_Float16)acc[mt][3][r]};
                *(f16x4*)(O + (size_t)row * G4 + (nb * 2 + wn) * 64 + n16 * 4) = pk;
            }
    }
}

// ---------------------------------------------------------------------------
// One-layer LSTM scan. grid = NB/4 blocks (4 batches each), 512 thr (8 waves,
// 2/SIMD). Wave v owns gate'-cols [64v,64v+64): tiles j, col n=64v+16j+l15.
// MFMA A rows m = batch m&3 (4x replication); D element r = batch r; lane
// (q,l15) owns batch q. Own-gate nonlinearity (gate gg=l15&3) then quad-DPP.
// Lane's unique state: (batch q, hu = 16v+4gg+(l15>>2)). Resident weights:
// ONLY whh (64 VGPR/lane) -> ~140 VGPR total, no spills.
// Phase A (hist!=0) writes h into the dead 384..511 tail of consumed xg rows.
// ---------------------------------------------------------------------------
__global__ __launch_bounds__(512, 2)
void lstm_phase(const _Float16* __restrict__ xg, const float* __restrict__ whh,
                const float* __restrict__ bias, const float* __restrict__ h0g,
                _Float16* hist, const float* __restrict__ fcw,
                const float* __restrict__ fcb, float* __restrict__ out, int dofc)
{
    __shared__ _Float16 __align__(16) hb[2][4][136];
    __shared__ float lds_r[4][128];

    const int b0 = blockIdx.x << 2;
    const int t = threadIdx.x, lane = t & 63, v = t >> 6;
    const int l15 = lane & 15, q = lane >> 4;
    const int u = l15 >> 2, gg = l15 & 3;

    // B-fragments of whh: wf[j][kt] for col n = 64v+16j+l15, k = 32kt+q*8+jj
    f16x8 wf[4][4];
    #pragma unroll
    for (int jj = 0; jj < 4; ++jj) {
        const int n  = 64 * v + 16 * jj + l15;
        const int pn = (n & 3) * 128 + (n >> 2);
        const float* wr = whh + (size_t)pn * H;
        #pragma unroll
        for (int kt = 0; kt < 4; ++kt)
            wf[jj][kt] = cvt8(wr + 32 * kt + q * 8);
    }
    float bj[4];
    #pragma unroll
    for (int jj = 0; jj < 4; ++jj)
        bj[jj] = bias[gg * 128 + 16 * v + 4 * jj + u];

    const bool  isg = (gg == 2);
    const float nsc = isg ? -2.0f : -1.0f;
    const float va  = isg ?  2.0f :  1.0f;
    const float vb  = isg ? -1.0f :  0.0f;
    const bool  s4  = (lane & 16) != 0;
    const bool  s5  = (lane & 32) != 0;
    const bool  o1  = (l15 & 1) != 0;
    const bool  o2  = (l15 & 2) != 0;

    hb[0][t >> 7][t & 127] = (_Float16)h0g[(size_t)(b0 + (t >> 7)) * H + (t & 127)];

    float c[4] = {0.f, 0.f, 0.f, 0.f};
    float hown = 0.f;
    const int hu_own = 16 * v + 4 * gg + u;

    const _Float16* xgp = xg + ((size_t)(b0 + q) * T) * G4 + v * 64 + l15 * 4;
    f16x4 x0 = *(const f16x4*)xgp;
    f16x4 x1 = *(const f16x4*)(xgp + G4);
    _Float16* hp = hist ? hist + ((size_t)(b0 + q) * T) * G4 + 384 + hu_own
                        : (_Float16*)0;

    __syncthreads();

    const f32x4 z = (f32x4){0.f, 0.f, 0.f, 0.f};

    for (int s = 0; s < T; ++s) {
        const int p = s & 1;
        f16x8 af[4];
        #pragma unroll
        for (int kt = 0; kt < 4; ++kt)                 // A row m -> batch m&3
            af[kt] = *(const f16x8*)(&hb[p][gg][32 * kt + q * 8]);

        f32x4 a0 = MFMA16(af[0], wf[0][0], z);
        f32x4 a1 = MFMA16(af[0], wf[1][0], z);
        f32x4 a2 = MFMA16(af[0], wf[2][0], z);
        f32x4 a3 = MFMA16(af[0], wf[3][0], z);
        #pragma unroll
        for (int kt = 1; kt < 4; ++kt) {
            a0 = MFMA16(af[kt], wf[0][kt], a0);
            a1 = MFMA16(af[kt], wf[1][kt], a1);
            a2 = MFMA16(af[kt], wf[2][kt], a2);
            a3 = MFMA16(af[kt], wf[3][kt], a3);
        }

        // element q of each acc = this lane's batch; + xg + bias
        float g[4];
        {
            float e01, e23;
            e01 = s4 ? a0[1] : a0[0]; e23 = s4 ? a0[3] : a0[2];
            g[0] = (s5 ? e23 : e01) + (float)x0[0] + bj[0];
            e01 = s4 ? a1[1] : a1[0]; e23 = s4 ? a1[3] : a1[2];
            g[1] = (s5 ? e23 : e01) + (float)x0[1] + bj[1];
            e01 = s4 ? a2[1] : a2[0]; e23 = s4 ? a2[3] : a2[2];
            g[2] = (s5 ? e23 : e01) + (float)x0[2] + bj[2];
            e01 = s4 ? a3[1] : a3[0]; e23 = s4 ? a3[3] : a3[2];
            g[3] = (s5 ? e23 : e01) + (float)x0[3] + bj[3];
        }

        x0 = x1;
        int sn = (s + 2 < T) ? (s + 2) : (T - 1);
        x1 = *(const f16x4*)(xgp + (size_t)sn * G4);

        // own-gate activation, quad-DPP broadcast, c update for all 4 hu
        float vl[4], no_[4];
        #pragma unroll
        for (int jj = 0; jj < 4; ++jj) {
            float uu = 1.0f / (1.0f + __expf(nsc * g[jj]));
            vl[jj] = fmaf(uu, va, vb);
        }
        #pragma unroll
        for (int jj = 0; jj < 4; ++jj) {
            float ni = DPPQ(vl[jj], 0x00);
            float nf = DPPQ(vl[jj], 0x55);
            float ng = DPPQ(vl[jj], 0xAA);
            no_[jj]  = DPPQ(vl[jj], 0xFF);
            c[jj] = nf * c[jj] + ni * ng;
        }
        float c_own  = o2 ? (o1 ? c[3]   : c[2])   : (o1 ? c[1]   : c[0]);
        float no_own = o2 ? (o1 ? no_[3] : no_[2]) : (o1 ? no_[1] : no_[0]);
        hown = no_own * tanhf_(c_own);

        hb[p ^ 1][q][hu_own] = (_Float16)hown;
        if (hp) hp[(size_t)s * G4] = (_Float16)hown;
        __syncthreads();
    }

    if (dofc) {
        lds_r[q][hu_own] = hown * fcw[hu_own];
        __syncthreads();
        if (t < 4) {
            float s_ = fcb[0];
            for (int k = 0; k < H; ++k) s_ += lds_r[t][k];
            out[b0 + t] = s_;
        }
    }
}

extern "C" void kernel_launch(void* const* d_in, const int* in_sizes, int n_in,
                              void* d_out, int out_size, void* d_ws, size_t ws_size,
                              hipStream_t stream)
{
    const float* x    = (const float*)d_in[0];
    const float* h0   = (const float*)d_in[1];
    const float* wih0 = (const float*)d_in[2];
    const float* whh0 = (const float*)d_in[3];
    const float* b0   = (const float*)d_in[4];
    const float* wih1 = (const float*)d_in[5];
    const float* whh1 = (const float*)d_in[6];
    const float* b1   = (const float*)d_in[7];
    const float* fcw  = (const float*)d_in[8];
    const float* fcb  = (const float*)d_in[9];
    float* out = (float*)d_out;

    _Float16* xg = (_Float16*)d_ws;   // [NBT][512] f16 = 256 MiB (hist in tail)

    // 1) xg0 = wih0 @ x  (permuted-packed f16)
    gemm_pp<64, 0><<<NBT / 128, 256, 0, stream>>>(x, DIN, wih0, xg);
    // 2) layer-0 scan; h0-history written into tail (cols 384..511) of xg rows
    lstm_phase<<<NB / 4, 512, 0, stream>>>(xg, whh0, b0, h0, xg,
                                           nullptr, nullptr, nullptr, 0);
    // 3) xg1 = wih1 @ h0hist (reads tail, overwrites rows in place, race-free)
    gemm_pp<128, 1><<<NBT / 128, 256, 0, stream>>>(xg + 384, G4, wih1, xg);
    // 4) layer-1 scan + fused FC
    lstm_phase<<<NB / 4, 512, 0, stream>>>(xg, whh1, b1, h0 + (size_t)NB * H,
                                           nullptr, fcw, fcb, out, 1);
}

// Round 6
// 1799.917 us; speedup vs baseline: 2.3966x; 1.1518x over previous
//
#include <hip/hip_runtime.h>
#include <math.h>

#define NB  256
#define T   1024
#define DIN 64
#define H   128
#define G4  512
#define NBT (NB * T)
#define TG4 (T * G4)      // elems per batch in packed xg
#define T4  (T * 4)       // elems per pc-group

typedef __attribute__((ext_vector_type(4))) float    f32x4;
typedef __attribute__((ext_vector_type(8))) _Float16 f16x8;
typedef __attribute__((ext_vector_type(4))) _Float16 f16x4;

#define DPPQ(v, CTRL) __int_as_float(__builtin_amdgcn_update_dpp(0, __float_as_int(v), (CTRL), 0xf, 0xf, true))
#define MFMA16(A, B, C) __builtin_amdgcn_mfma_f32_16x16x32_f16((A), (B), (C), 0, 0, 0)

__device__ __forceinline__ float tanhf_(float x) { return 2.0f / (1.0f + __expf(-2.0f * x)) - 1.0f; }

__device__ __forceinline__ f16x8 cvt8(const float* p) {
    float4 v0 = *(const float4*)p;
    float4 v1 = *(const float4*)(p + 4);
    return (f16x8){(_Float16)v0.x, (_Float16)v0.y, (_Float16)v0.z, (_Float16)v0.w,
                   (_Float16)v1.x, (_Float16)v1.y, (_Float16)v1.z, (_Float16)v1.w};
}

// ---------------------------------------------------------------------------
// GEMM -> s-major packed f16 xg: addr(b,pc,s,e) = b*TG4 + pc*T4 + s*4 + e,
// where col n -> pc = (n>>6)*16 + (n&15), e = (n>>4)&3, and W-row perm
// pn = (n&3)*128 + (n>>2) (gate' order). AH=1 reads A from packed hist
// (groups 0..31 of the same buffer) and overwrites its own s-range in place
// (reads staged to LDS before any write; s-ranges disjoint across blocks).
// ---------------------------------------------------------------------------
template<int K, int AH>
__global__ __launch_bounds__(256, 2)
void gemm_pp(const void* __restrict__ A, const float* __restrict__ W,
             _Float16* __restrict__ O)
{
    __shared__ _Float16 __align__(16) sA[128][136];
    __shared__ _Float16 __align__(16) sW[128][72];

    const int m0 = blockIdx.x << 7;
    const int j = threadIdx.x;
    const int lane = j & 63, wv = j >> 6;
    const int wm = wv >> 1, wn = wv & 1;
    const int q = lane >> 4, n16 = lane & 15;
    const int bb = m0 >> 10, s0 = m0 & (T - 1);

    if constexpr (AH) {
        // hist: A[s][k] = buf[bb*TG4 + (k>>2)*T4 + s*4 + (k&3)]
        const _Float16* Ah = (const _Float16*)A;
        #pragma unroll
        for (int it = 0; it < 8; ++it) {
            int idx = j + it * 256;              // 0..2047
            int r = idx & 127, gp = idx >> 7;    // row s-local, group-pair 0..15
            const _Float16* base = Ah + (size_t)bb * TG4 + (size_t)(s0 + r) * 4;
            f16x4 a = *(const f16x4*)(base + (size_t)(2 * gp) * T4);
            f16x4 b = *(const f16x4*)(base + (size_t)(2 * gp + 1) * T4);
            *(f16x8*)&sA[r][8 * gp] = (f16x8){a[0], a[1], a[2], a[3],
                                              b[0], b[1], b[2], b[3]};
        }
    } else {
        const float* Af = (const float*)A;
        #pragma unroll
        for (int it = 0; it < 8; ++it) {         // 128 rows x 16 float4 chunks
            int idx = j + it * 256;
            int r = idx >> 4, kc = (idx & 15) << 2;
            float4 va = *(const float4*)(Af + (size_t)(m0 + r) * K + kc);
            *(f16x4*)&sA[r][kc] = (f16x4){(_Float16)va.x, (_Float16)va.y,
                                          (_Float16)va.z, (_Float16)va.w};
        }
    }

    for (int nb = 0; nb < 4; ++nb) {
        f32x4 acc[4][4];
        #pragma unroll
        for (int a = 0; a < 4; ++a)
            #pragma unroll
            for (int bq = 0; bq < 4; ++bq) acc[a][bq] = (f32x4){0.f, 0.f, 0.f, 0.f};

        #pragma unroll
        for (int kp = 0; kp < K / 64; ++kp) {
            __syncthreads();
            #pragma unroll
            for (int it = 0; it < 8; ++it) {
                int idx = j + it * 256;
                int r = idx >> 4, kc = (idx & 15) << 2;
                int n = (nb << 7) + r, pn = (n & 3) * 128 + (n >> 2);
                float4 vw = *(const float4*)(W + (size_t)pn * K + kp * 64 + kc);
                *(f16x4*)&sW[r][kc] = (f16x4){(_Float16)vw.x, (_Float16)vw.y,
                                              (_Float16)vw.z, (_Float16)vw.w};
            }
            __syncthreads();
            #pragma unroll
            for (int kh = 0; kh < 2; ++kh) {
                const int kk = kh * 32 + q * 8;
                f16x8 a[4], bf[4];
                #pragma unroll
                for (int mt = 0; mt < 4; ++mt)
                    a[mt] = *(const f16x8*)&sA[wm * 64 + mt * 16 + n16][kp * 64 + kk];
                #pragma unroll
                for (int nt = 0; nt < 4; ++nt)
                    bf[nt] = *(const f16x8*)&sW[wn * 64 + nt * 16 + n16][kk];
                #pragma unroll
                for (int nt = 0; nt < 4; ++nt)
                    #pragma unroll
                    for (int mt = 0; mt < 4; ++mt)
                        acc[mt][nt] = MFMA16(a[mt], bf[nt], acc[mt][nt]);
            }
        }
        // epilogue: pc-group = (nb*2+wn)*16 + n16, elem = nt; s-major pack
        const int grp = (nb * 2 + wn) * 16 + n16;
        #pragma unroll
        for (int mt = 0; mt < 4; ++mt)
            #pragma unroll
            for (int r = 0; r < 4; ++r) {
                int row = m0 + wm * 64 + mt * 16 + q * 4 + r;
                f16x4 pk = {(_Float16)acc[mt][0][r], (_Float16)acc[mt][1][r],
                            (_Float16)acc[mt][2][r], (_Float16)acc[mt][3][r]};
                *(f16x4*)(O + (size_t)bb * TG4 + (size_t)grp * T4
                            + (size_t)(row & (T - 1)) * 4) = pk;
            }
    }
}

// ---------------------------------------------------------------------------
// One-layer LSTM scan. 64 blocks (4 batches each), 512 thr. Wave v owns
// gate'-cols [64v,64v+64); lane (q,l15) computes cols 64v+16j+l15 (j=0..3)
// for batch q; A rows replicate batch m&3; D elem q = own batch (5q&3==q).
// xg read from s-major packed layout via an 8-step register ring (4x f16x8,
// compile-time indexed) -> prefetch distance 7 steps. hb stride 144 (2-way
// max banks). 2-deep MFMA chains merged in the select domain. Phase A
// writes h-history into consumed xg groups 0..31 (slot s, 7-step slack).
// ---------------------------------------------------------------------------
__global__ __launch_bounds__(512, 2)
void lstm_phase(const _Float16* __restrict__ xg, const float* __restrict__ whh,
                const float* __restrict__ bias, const float* __restrict__ h0g,
                _Float16* hist, const float* __restrict__ fcw,
                const float* __restrict__ fcb, float* __restrict__ out, int dofc)
{
    __shared__ _Float16 __align__(16) hb[2][4][144];
    __shared__ float lds_r[4][128];

    const int b0 = blockIdx.x << 2;
    const int t = threadIdx.x, lane = t & 63, v = t >> 6;
    const int l15 = lane & 15, q = lane >> 4;
    const int u = l15 >> 2, gg = l15 & 3;

    // B-fragments of whh: wf[j][kt] for col n = 64v+16j+l15, k = 32kt+q*8+jj
    f16x8 wf[4][4];
    #pragma unroll
    for (int jj = 0; jj < 4; ++jj) {
        const int n  = 64 * v + 16 * jj + l15;
        const int pn = (n & 3) * 128 + (n >> 2);
        const float* wr = whh + (size_t)pn * H;
        #pragma unroll
        for (int kt = 0; kt < 4; ++kt)
            wf[jj][kt] = cvt8(wr + 32 * kt + q * 8);
    }
    float bj[4];
    #pragma unroll
    for (int jj = 0; jj < 4; ++jj)
        bj[jj] = bias[gg * 128 + 16 * v + 4 * jj + u];

    const bool  isg = (gg == 2);
    const float nsc = isg ? -2.0f : -1.0f;
    const float va  = isg ?  2.0f :  1.0f;
    const float vb  = isg ? -1.0f :  0.0f;
    const bool  s4  = (lane & 16) != 0;
    const bool  s5  = (lane & 32) != 0;
    const bool  o1  = (l15 & 1) != 0;
    const bool  o2  = (l15 & 2) != 0;

    hb[0][t >> 7][t & 127] = (_Float16)h0g[(size_t)(b0 + (t >> 7)) * H + (t & 127)];

    float c[4] = {0.f, 0.f, 0.f, 0.f};
    float hown = 0.f;
    const int hu_own = 16 * v + 4 * gg + u;

    // s-major packed xg stream for (batch q, pc-group v*16+l15)
    const _Float16* xgp = xg + (size_t)(b0 + q) * TG4 + (size_t)(v * 16 + l15) * T4;
    f16x8 xr0 = *(const f16x8*)(xgp + 0);    // steps 0,1
    f16x8 xr1 = *(const f16x8*)(xgp + 8);    // steps 2,3
    f16x8 xr2 = *(const f16x8*)(xgp + 16);   // steps 4,5
    f16x8 xr3 = *(const f16x8*)(xgp + 24);   // steps 6,7

    _Float16* hp = hist ? hist + (size_t)(b0 + q) * TG4
                               + (size_t)(hu_own >> 2) * T4 + (hu_own & 3)
                        : (_Float16*)0;

    __syncthreads();

    const f32x4 z = (f32x4){0.f, 0.f, 0.f, 0.f};

    #define SELQ(a) (s5 ? (s4 ? (a)[3] : (a)[2]) : (s4 ? (a)[1] : (a)[0]))

    for (int sb = 0; sb < T; sb += 8) {
        #pragma unroll
        for (int ss = 0; ss < 8; ++ss) {
            const int s = sb + ss;
            const int p = s & 1;

            f16x8 xcur = (ss < 2) ? xr0 : (ss < 4) ? xr1 : (ss < 6) ? xr2 : xr3;
            float xv[4];
            #pragma unroll
            for (int jj = 0; jj < 4; ++jj)
                xv[jj] = (float)xcur[(ss & 1) * 4 + jj];

            f16x8 af[4];
            #pragma unroll
            for (int kt = 0; kt < 4; ++kt)
                af[kt] = *(const f16x8*)(&hb[p][gg][32 * kt + q * 8]);

            // two 2-deep K-chains per j-tile, merged after select
            f32x4 aA0 = MFMA16(af[0], wf[0][0], z);
            f32x4 aA1 = MFMA16(af[0], wf[1][0], z);
            f32x4 aA2 = MFMA16(af[0], wf[2][0], z);
            f32x4 aA3 = MFMA16(af[0], wf[3][0], z);
            f32x4 aB0 = MFMA16(af[2], wf[0][2], z);
            f32x4 aB1 = MFMA16(af[2], wf[1][2], z);
            f32x4 aB2 = MFMA16(af[2], wf[2][2], z);
            f32x4 aB3 = MFMA16(af[2], wf[3][2], z);
            aA0 = MFMA16(af[1], wf[0][1], aA0);
            aA1 = MFMA16(af[1], wf[1][1], aA1);
            aA2 = MFMA16(af[1], wf[2][1], aA2);
            aA3 = MFMA16(af[1], wf[3][1], aA3);
            aB0 = MFMA16(af[3], wf[0][3], aB0);
            aB1 = MFMA16(af[3], wf[1][3], aB1);
            aB2 = MFMA16(af[3], wf[2][3], aB2);
            aB3 = MFMA16(af[3], wf[3][3], aB3);

            // ring reload (distance 7); clamp keeps addresses in-bounds
            if (ss == 1) { int i0 = sb + 8;  if (i0 > T - 2) i0 = T - 2; xr0 = *(const f16x8*)(xgp + (size_t)i0 * 4); }
            if (ss == 3) { int i1 = sb + 10; if (i1 > T - 2) i1 = T - 2; xr1 = *(const f16x8*)(xgp + (size_t)i1 * 4); }
            if (ss == 5) { int i2 = sb + 12; if (i2 > T - 2) i2 = T - 2; xr2 = *(const f16x8*)(xgp + (size_t)i2 * 4); }
            if (ss == 7) { int i3 = sb + 14; if (i3 > T - 2) i3 = T - 2; xr3 = *(const f16x8*)(xgp + (size_t)i3 * 4); }

            float g[4];
            g[0] = SELQ(aA0) + SELQ(aB0) + xv[0] + bj[0];
            g[1] = SELQ(aA1) + SELQ(aB1) + xv[1] + bj[1];
            g[2] = SELQ(aA2) + SELQ(aB2) + xv[2] + bj[2];
            g[3] = SELQ(aA3) + SELQ(aB3) + xv[3] + bj[3];

            // own-gate activation, quad-DPP broadcast, c update
            float vl[4], no_[4];
            #pragma unroll
            for (int jj = 0; jj < 4; ++jj) {
                float uu = 1.0f / (1.0f + __expf(nsc * g[jj]));
                vl[jj] = fmaf(uu, va, vb);
            }
            #pragma unroll
            for (int jj = 0; jj < 4; ++jj) {
                float ni = DPPQ(vl[jj], 0x00);
                float nf = DPPQ(vl[jj], 0x55);
                float ng = DPPQ(vl[jj], 0xAA);
                no_[jj]  = DPPQ(vl[jj], 0xFF);
                c[jj] = nf * c[jj] + ni * ng;
            }
            float c_own  = o2 ? (o1 ? c[3]   : c[2])   : (o1 ? c[1]   : c[0]);
            float no_own = o2 ? (o1 ? no_[3] : no_[2]) : (o1 ? no_[1] : no_[0]);
            hown = no_own * tanhf_(c_own);

            hb[p ^ 1][q][hu_own] = (_Float16)hown;
            if (hp) hp[(size_t)s * 4] = (_Float16)hown;
            __syncthreads();
        }
    }

    if (dofc) {
        lds_r[q][hu_own] = hown * fcw[hu_own];
        __syncthreads();
        if (t < 4) {
            float s_ = fcb[0];
            for (int k = 0; k < H; ++k) s_ += lds_r[t][k];
            out[b0 + t] = s_;
        }
    }
}

extern "C" void kernel_launch(void* const* d_in, const int* in_sizes, int n_in,
                              void* d_out, int out_size, void* d_ws, size_t ws_size,
                              hipStream_t stream)
{
    const float* x    = (const float*)d_in[0];
    const float* h0   = (const float*)d_in[1];
    const float* wih0 = (const float*)d_in[2];
    const float* whh0 = (const float*)d_in[3];
    const float* b0   = (const float*)d_in[4];
    const float* wih1 = (const float*)d_in[5];
    const float* whh1 = (const float*)d_in[6];
    const float* b1   = (const float*)d_in[7];
    const float* fcw  = (const float*)d_in[8];
    const float* fcb  = (const float*)d_in[9];
    float* out = (float*)d_out;

    _Float16* xg = (_Float16*)d_ws;   // [NB][128 groups][T][4] f16 = 256 MiB

    // 1) xg0 = wih0 @ x  (s-major packed f16)
    gemm_pp<64, 0><<<NBT / 128, 256, 0, stream>>>(x, wih0, xg);
    // 2) layer-0 scan; h0-history into consumed groups 0..31 of xg
    lstm_phase<<<NB / 4, 512, 0, stream>>>(xg, whh0, b0, h0, xg,
                                           nullptr, nullptr, nullptr, 0);
    // 3) xg1 = wih1 @ h0hist (in place, block-local s-ranges, race-free)
    gemm_pp<128, 1><<<NBT / 128, 256, 0, stream>>>(xg, wih1, xg);
    // 4) layer-1 scan + fused FC
    lstm_phase<<<NB / 4, 512, 0, stream>>>(xg, whh1, b1, h0 + (size_t)NB * H,
                                           nullptr, fcw, fcb, out, 1);
}

// Round 7
// 1795.121 us; speedup vs baseline: 2.4031x; 1.0027x over previous
//
#include <hip/hip_runtime.h>
#include <math.h>

#define NB  256
#define T   1024
#define DIN 64
#define H   128
#define G4  512
#define NBT (NB * T)
#define TG4 (T * G4)      // elems per batch in packed xg
#define T4  (T * 4)       // elems per pc-group

typedef __attribute__((ext_vector_type(4))) float    f32x4;
typedef __attribute__((ext_vector_type(8))) _Float16 f16x8;
typedef __attribute__((ext_vector_type(4))) _Float16 f16x4;

#define DPPQ(v, CTRL) __int_as_float(__builtin_amdgcn_update_dpp(0, __float_as_int(v), (CTRL), 0xf, 0xf, true))
#define MFMA16(A, B, C) __builtin_amdgcn_mfma_f32_16x16x32_f16((A), (B), (C), 0, 0, 0)

__device__ __forceinline__ float tanhf_(float x) { return 2.0f / (1.0f + __expf(-2.0f * x)) - 1.0f; }

// Raw workgroup barrier WITHOUT the vmcnt(0) drain __syncthreads implies.
// Only LDS ordering (hb ds_write -> cross-wave ds_read) must be protected:
// lgkmcnt(0) then s_barrier. Global loads/stores stay in flight across it;
// the compiler's counted vmcnt waits at the actual consumption point.
__device__ __forceinline__ void wg_barrier() {
    asm volatile("s_waitcnt lgkmcnt(0)" ::: "memory");
    __builtin_amdgcn_s_barrier();
}

__device__ __forceinline__ f16x8 cvt8(const float* p) {
    float4 v0 = *(const float4*)p;
    float4 v1 = *(const float4*)(p + 4);
    return (f16x8){(_Float16)v0.x, (_Float16)v0.y, (_Float16)v0.z, (_Float16)v0.w,
                   (_Float16)v1.x, (_Float16)v1.y, (_Float16)v1.z, (_Float16)v1.w};
}

// ---------------------------------------------------------------------------
// GEMM -> s-major packed f16 xg: addr(b,pc,s,e) = b*TG4 + pc*T4 + s*4 + e,
// where col n -> pc = (n>>6)*16 + (n&15), e = (n>>4)&3, and W-row perm
// pn = (n&3)*128 + (n>>2) (gate' order). AH=1 reads A from packed hist
// (groups 0..31 of the same buffer) and overwrites its own s-range in place
// (reads staged to LDS before any write; s-ranges disjoint across blocks).
// ---------------------------------------------------------------------------
template<int K, int AH>
__global__ __launch_bounds__(256, 2)
void gemm_pp(const void* __restrict__ A, const float* __restrict__ W,
             _Float16* __restrict__ O)
{
    __shared__ _Float16 __align__(16) sA[128][136];
    __shared__ _Float16 __align__(16) sW[128][72];

    const int m0 = blockIdx.x << 7;
    const int j = threadIdx.x;
    const int lane = j & 63, wv = j >> 6;
    const int wm = wv >> 1, wn = wv & 1;
    const int q = lane >> 4, n16 = lane & 15;
    const int bb = m0 >> 10, s0 = m0 & (T - 1);

    if constexpr (AH) {
        // hist: A[s][k] = buf[bb*TG4 + (k>>2)*T4 + s*4 + (k&3)]
        const _Float16* Ah = (const _Float16*)A;
        #pragma unroll
        for (int it = 0; it < 8; ++it) {
            int idx = j + it * 256;              // 0..2047
            int r = idx & 127, gp = idx >> 7;    // row s-local, group-pair 0..15
            const _Float16* base = Ah + (size_t)bb * TG4 + (size_t)(s0 + r) * 4;
            f16x4 a = *(const f16x4*)(base + (size_t)(2 * gp) * T4);
            f16x4 b = *(const f16x4*)(base + (size_t)(2 * gp + 1) * T4);
            *(f16x8*)&sA[r][8 * gp] = (f16x8){a[0], a[1], a[2], a[3],
                                              b[0], b[1], b[2], b[3]};
        }
    } else {
        const float* Af = (const float*)A;
        #pragma unroll
        for (int it = 0; it < 8; ++it) {         // 128 rows x 16 float4 chunks
            int idx = j + it * 256;
            int r = idx >> 4, kc = (idx & 15) << 2;
            float4 va = *(const float4*)(Af + (size_t)(m0 + r) * K + kc);
            *(f16x4*)&sA[r][kc] = (f16x4){(_Float16)va.x, (_Float16)va.y,
                                          (_Float16)va.z, (_Float16)va.w};
        }
    }

    for (int nb = 0; nb < 4; ++nb) {
        f32x4 acc[4][4];
        #pragma unroll
        for (int a = 0; a < 4; ++a)
            #pragma unroll
            for (int bq = 0; bq < 4; ++bq) acc[a][bq] = (f32x4){0.f, 0.f, 0.f, 0.f};

        #pragma unroll
        for (int kp = 0; kp < K / 64; ++kp) {
            __syncthreads();
            #pragma unroll
            for (int it = 0; it < 8; ++it) {
                int idx = j + it * 256;
                int r = idx >> 4, kc = (idx & 15) << 2;
                int n = (nb << 7) + r, pn = (n & 3) * 128 + (n >> 2);
                float4 vw = *(const float4*)(W + (size_t)pn * K + kp * 64 + kc);
                *(f16x4*)&sW[r][kc] = (f16x4){(_Float16)vw.x, (_Float16)vw.y,
                                              (_Float16)vw.z, (_Float16)vw.w};
            }
            __syncthreads();
            #pragma unroll
            for (int kh = 0; kh < 2; ++kh) {
                const int kk = kh * 32 + q * 8;
                f16x8 a[4], bf[4];
                #pragma unroll
                for (int mt = 0; mt < 4; ++mt)
                    a[mt] = *(const f16x8*)&sA[wm * 64 + mt * 16 + n16][kp * 64 + kk];
                #pragma unroll
                for (int nt = 0; nt < 4; ++nt)
                    bf[nt] = *(const f16x8*)&sW[wn * 64 + nt * 16 + n16][kk];
                #pragma unroll
                for (int nt = 0; nt < 4; ++nt)
                    #pragma unroll
                    for (int mt = 0; mt < 4; ++mt)
                        acc[mt][nt] = MFMA16(a[mt], bf[nt], acc[mt][nt]);
            }
        }
        // epilogue: pc-group = (nb*2+wn)*16 + n16, elem = nt; s-major pack
        const int grp = (nb * 2 + wn) * 16 + n16;
        #pragma unroll
        for (int mt = 0; mt < 4; ++mt)
            #pragma unroll
            for (int r = 0; r < 4; ++r) {
                int row = m0 + wm * 64 + mt * 16 + q * 4 + r;
                f16x4 pk = {(_Float16)acc[mt][0][r], (_Float16)acc[mt][1][r],
                            (_Float16)acc[mt][2][r], (_Float16)acc[mt][3][r]};
                *(f16x4*)(O + (size_t)bb * TG4 + (size_t)grp * T4
                            + (size_t)(row & (T - 1)) * 4) = pk;
            }
    }
}

// ---------------------------------------------------------------------------
// One-layer LSTM scan. 64 blocks (4 batches each), 512 thr. Wave v owns
// gate'-cols [64v,64v+64); lane (q,l15) computes cols 64v+16j+l15 (j=0..3)
// for batch q; A rows replicate batch m&3; D elem q = own batch.
// xg read from s-major packed layout via an 8-step register ring (4x f16x8,
// compile-time indexed) -> prefetch distance 7 steps, genuinely in flight
// across the raw per-step barrier (no vmcnt drain). hb stride 144.
// Phase A writes h-history into consumed xg groups 0..31.
// ---------------------------------------------------------------------------
__global__ __launch_bounds__(512, 2)
void lstm_phase(const _Float16* __restrict__ xg, const float* __restrict__ whh,
                const float* __restrict__ bias, const float* __restrict__ h0g,
                _Float16* hist, const float* __restrict__ fcw,
                const float* __restrict__ fcb, float* __restrict__ out, int dofc)
{
    __shared__ _Float16 __align__(16) hb[2][4][144];
    __shared__ float lds_r[4][128];

    const int b0 = blockIdx.x << 2;
    const int t = threadIdx.x, lane = t & 63, v = t >> 6;
    const int l15 = lane & 15, q = lane >> 4;
    const int u = l15 >> 2, gg = l15 & 3;

    // B-fragments of whh: wf[j][kt] for col n = 64v+16j+l15, k = 32kt+q*8+jj
    f16x8 wf[4][4];
    #pragma unroll
    for (int jj = 0; jj < 4; ++jj) {
        const int n  = 64 * v + 16 * jj + l15;
        const int pn = (n & 3) * 128 + (n >> 2);
        const float* wr = whh + (size_t)pn * H;
        #pragma unroll
        for (int kt = 0; kt < 4; ++kt)
            wf[jj][kt] = cvt8(wr + 32 * kt + q * 8);
    }
    float bj[4];
    #pragma unroll
    for (int jj = 0; jj < 4; ++jj)
        bj[jj] = bias[gg * 128 + 16 * v + 4 * jj + u];

    const bool  isg = (gg == 2);
    const float nsc = isg ? -2.0f : -1.0f;
    const float va  = isg ?  2.0f :  1.0f;
    const float vb  = isg ? -1.0f :  0.0f;
    const bool  s4  = (lane & 16) != 0;
    const bool  s5  = (lane & 32) != 0;
    const bool  o1  = (l15 & 1) != 0;
    const bool  o2  = (l15 & 2) != 0;

    hb[0][t >> 7][t & 127] = (_Float16)h0g[(size_t)(b0 + (t >> 7)) * H + (t & 127)];

    float c[4] = {0.f, 0.f, 0.f, 0.f};
    float hown = 0.f;
    const int hu_own = 16 * v + 4 * gg + u;

    // s-major packed xg stream for (batch q, pc-group v*16+l15)
    const _Float16* xgp = xg + (size_t)(b0 + q) * TG4 + (size_t)(v * 16 + l15) * T4;
    f16x8 xr0 = *(const f16x8*)(xgp + 0);    // steps 0,1
    f16x8 xr1 = *(const f16x8*)(xgp + 8);    // steps 2,3
    f16x8 xr2 = *(const f16x8*)(xgp + 16);   // steps 4,5
    f16x8 xr3 = *(const f16x8*)(xgp + 24);   // steps 6,7

    _Float16* hp = hist ? hist + (size_t)(b0 + q) * TG4
                               + (size_t)(hu_own >> 2) * T4 + (hu_own & 3)
                        : (_Float16*)0;

    __syncthreads();

    const f32x4 z = (f32x4){0.f, 0.f, 0.f, 0.f};

    #define SELQ(a) (s5 ? (s4 ? (a)[3] : (a)[2]) : (s4 ? (a)[1] : (a)[0]))

    for (int sb = 0; sb < T; sb += 8) {
        #pragma unroll
        for (int ss = 0; ss < 8; ++ss) {
            const int s = sb + ss;
            const int p = s & 1;

            f16x8 xcur = (ss < 2) ? xr0 : (ss < 4) ? xr1 : (ss < 6) ? xr2 : xr3;
            float xv[4];
            #pragma unroll
            for (int jj = 0; jj < 4; ++jj)
                xv[jj] = (float)xcur[(ss & 1) * 4 + jj];

            f16x8 af[4];
            #pragma unroll
            for (int kt = 0; kt < 4; ++kt)
                af[kt] = *(const f16x8*)(&hb[p][gg][32 * kt + q * 8]);

            // two 2-deep K-chains per j-tile, merged after select
            f32x4 aA0 = MFMA16(af[0], wf[0][0], z);
            f32x4 aA1 = MFMA16(af[0], wf[1][0], z);
            f32x4 aA2 = MFMA16(af[0], wf[2][0], z);
            f32x4 aA3 = MFMA16(af[0], wf[3][0], z);
            f32x4 aB0 = MFMA16(af[2], wf[0][2], z);
            f32x4 aB1 = MFMA16(af[2], wf[1][2], z);
            f32x4 aB2 = MFMA16(af[2], wf[2][2], z);
            f32x4 aB3 = MFMA16(af[2], wf[3][2], z);
            aA0 = MFMA16(af[1], wf[0][1], aA0);
            aA1 = MFMA16(af[1], wf[1][1], aA1);
            aA2 = MFMA16(af[1], wf[2][1], aA2);
            aA3 = MFMA16(af[1], wf[3][1], aA3);
            aB0 = MFMA16(af[3], wf[0][3], aB0);
            aB1 = MFMA16(af[3], wf[1][3], aB1);
            aB2 = MFMA16(af[3], wf[2][3], aB2);
            aB3 = MFMA16(af[3], wf[3][3], aB3);

            // ring reload (distance 7); clamp keeps addresses in-bounds
            if (ss == 1) { int i0 = sb + 8;  if (i0 > T - 2) i0 = T - 2; xr0 = *(const f16x8*)(xgp + (size_t)i0 * 4); }
            if (ss == 3) { int i1 = sb + 10; if (i1 > T - 2) i1 = T - 2; xr1 = *(const f16x8*)(xgp + (size_t)i1 * 4); }
            if (ss == 5) { int i2 = sb + 12; if (i2 > T - 2) i2 = T - 2; xr2 = *(const f16x8*)(xgp + (size_t)i2 * 4); }
            if (ss == 7) { int i3 = sb + 14; if (i3 > T - 2) i3 = T - 2; xr3 = *(const f16x8*)(xgp + (size_t)i3 * 4); }

            float g[4];
            g[0] = SELQ(aA0) + SELQ(aB0) + xv[0] + bj[0];
            g[1] = SELQ(aA1) + SELQ(aB1) + xv[1] + bj[1];
            g[2] = SELQ(aA2) + SELQ(aB2) + xv[2] + bj[2];
            g[3] = SELQ(aA3) + SELQ(aB3) + xv[3] + bj[3];

            // own-gate activation, quad-DPP broadcast, c update
            float vl[4], no_[4];
            #pragma unroll
            for (int jj = 0; jj < 4; ++jj) {
                float uu = 1.0f / (1.0f + __expf(nsc * g[jj]));
                vl[jj] = fmaf(uu, va, vb);
            }
            #pragma unroll
            for (int jj = 0; jj < 4; ++jj) {
                float ni = DPPQ(vl[jj], 0x00);
                float nf = DPPQ(vl[jj], 0x55);
                float ng = DPPQ(vl[jj], 0xAA);
                no_[jj]  = DPPQ(vl[jj], 0xFF);
                c[jj] = nf * c[jj] + ni * ng;
            }
            float c_own  = o2 ? (o1 ? c[3]   : c[2])   : (o1 ? c[1]   : c[0]);
            float no_own = o2 ? (o1 ? no_[3] : no_[2]) : (o1 ? no_[1] : no_[0]);
            hown = no_own * tanhf_(c_own);

            hb[p ^ 1][q][hu_own] = (_Float16)hown;
            if (hp) hp[(size_t)s * 4] = (_Float16)hown;

            wg_barrier();   // lgkmcnt(0) + s_barrier; globals stay in flight
        }
    }

    if (dofc) {
        lds_r[q][hu_own] = hown * fcw[hu_own];
        __syncthreads();
        if (t < 4) {
            float s_ = fcb[0];
            for (int k = 0; k < H; ++k) s_ += lds_r[t][k];
            out[b0 + t] = s_;
        }
    }
}

extern "C" void kernel_launch(void* const* d_in, const int* in_sizes, int n_in,
                              void* d_out, int out_size, void* d_ws, size_t ws_size,
                              hipStream_t stream)
{
    const float* x    = (const float*)d_in[0];
    const float* h0   = (const float*)d_in[1];
    const float* wih0 = (const float*)d_in[2];
    const float* whh0 = (const float*)d_in[3];
    const float* b0   = (const float*)d_in[4];
    const float* wih1 = (const float*)d_in[5];
    const float* whh1 = (const float*)d_in[6];
    const float* b1   = (const float*)d_in[7];
    const float* fcw  = (const float*)d_in[8];
    const float* fcb  = (const float*)d_in[9];
    float* out = (float*)d_out;

    _Float16* xg = (_Float16*)d_ws;   // [NB][128 groups][T][4] f16 = 256 MiB

    // 1) xg0 = wih0 @ x  (s-major packed f16)
    gemm_pp<64, 0><<<NBT / 128, 256, 0, stream>>>(x, wih0, xg);
    // 2) layer-0 scan; h0-history into consumed groups 0..31 of xg
    lstm_phase<<<NB / 4, 512, 0, stream>>>(xg, whh0, b0, h0, xg,
                                           nullptr, nullptr, nullptr, 0);
    // 3) xg1 = wih1 @ h0hist (in place, block-local s-ranges, race-free)
    gemm_pp<128, 1><<<NBT / 128, 256, 0, stream>>>(xg, wih1, xg);
    // 4) layer-1 scan + fused FC
    lstm_phase<<<NB / 4, 512, 0, stream>>>(xg, whh1, b1, h0 + (size_t)NB * H,
                                           nullptr, fcw, fcb, out, 1);
}

// Round 8
// 1279.823 us; speedup vs baseline: 3.3706x; 1.4026x over previous
//
#include <hip/hip_runtime.h>
#include <math.h>

#define NB  256
#define T   1024
#define DIN 64
#define H   128
#define G4  512
#define NBT (NB * T)
#define TG4 (T * G4)      // elems per batch in packed xg (1 MiB / 2B)

typedef __attribute__((ext_vector_type(4))) float    f32x4;
typedef __attribute__((ext_vector_type(8))) _Float16 f16x8;
typedef __attribute__((ext_vector_type(4))) _Float16 f16x4;
typedef __attribute__((ext_vector_type(2))) _Float16 f16x2;

#define DPPQ(v, CTRL) __int_as_float(__builtin_amdgcn_update_dpp(0, __float_as_int(v), (CTRL), 0xf, 0xf, true))
#define MFMA16(A, B, C) __builtin_amdgcn_mfma_f32_16x16x32_f16((A), (B), (C), 0, 0, 0)

__device__ __forceinline__ float tanhf_(float x) { return 2.0f / (1.0f + __expf(-2.0f * x)) - 1.0f; }

__device__ __forceinline__ void wg_barrier() {
    asm volatile("s_waitcnt lgkmcnt(0)" ::: "memory");
    __builtin_amdgcn_s_barrier();
}

__device__ __forceinline__ f16x8 cvt8(const float* p) {
    float4 v0 = *(const float4*)p;
    float4 v1 = *(const float4*)(p + 4);
    return (f16x8){(_Float16)v0.x, (_Float16)v0.y, (_Float16)v0.z, (_Float16)v0.w,
                   (_Float16)v1.x, (_Float16)v1.y, (_Float16)v1.z, (_Float16)v1.w};
}

// ---------------------------------------------------------------------------
// xg layout: addr(b, grp, s, e) = b*TG4 + grp*2048 + s*2 + e, where gate' col
// n -> grp = (n>>7)*64 + ((n>>5)&3)*16 + (n&15), e = (n>>4)&1.
// Scan lane (v,q,l15) reads grp = v*64+q*16+l15: its two cols (tiles 2q,2q+1)
// are contiguous in s -> one b128 = 4 steps.
// hist (h0 history) overlays xg grps 0..63: addr = b*TG4 + (hu>>1)*2048 +
// s*2 + (hu&1) -- same 2-elem/step rate+direction as the reader => the
// overlay is read-before-write safe at every position.
// ---------------------------------------------------------------------------
template<int K, int AH>
__global__ __launch_bounds__(256, 2)
void gemm_pp(const void* __restrict__ A, const float* __restrict__ W,
             _Float16* __restrict__ O)
{
    __shared__ _Float16 __align__(16) sA[128][136];
    __shared__ _Float16 __align__(16) sW[128][72];

    const int m0 = blockIdx.x << 7;
    const int j = threadIdx.x;
    const int lane = j & 63, wv = j >> 6;
    const int wm = wv >> 1, wn = wv & 1;
    const int q = lane >> 4, n16 = lane & 15;
    const int bb = m0 >> 10, s0 = m0 & (T - 1);
    const size_t bO = (size_t)bb * TG4;

    if constexpr (AH) {
        // hist pair layout: A[s][k] = buf[bO + (k>>1)*2048 + s*2 + (k&1)]
        const _Float16* Ah = (const _Float16*)A;
        #pragma unroll
        for (int it = 0; it < 8; ++it) {
            int idx = j + it * 256;              // 64 kp x 32 sblk
            int kp = idx & 63, sblk = idx >> 6;
            f16x8 xv8 = *(const f16x8*)(Ah + bO + (size_t)kp * 2048
                                        + (size_t)(s0 + sblk * 4) * 2);
            #pragma unroll
            for (int d = 0; d < 4; ++d)
                *(f16x2*)&sA[sblk * 4 + d][2 * kp] = (f16x2){xv8[2 * d], xv8[2 * d + 1]};
        }
    } else {
        const float* Af = (const float*)A;
        #pragma unroll
        for (int it = 0; it < 8; ++it) {         // 128 rows x 16 float4 chunks
            int idx = j + it * 256;
            int r = idx >> 4, kc = (idx & 15) << 2;
            float4 va = *(const float4*)(Af + (size_t)(m0 + r) * K + kc);
            *(f16x4*)&sA[r][kc] = (f16x4){(_Float16)va.x, (_Float16)va.y,
                                          (_Float16)va.z, (_Float16)va.w};
        }
    }

    for (int nb = 0; nb < 4; ++nb) {
        f32x4 acc[4][4];
        #pragma unroll
        for (int a = 0; a < 4; ++a)
            #pragma unroll
            for (int bq = 0; bq < 4; ++bq) acc[a][bq] = (f32x4){0.f, 0.f, 0.f, 0.f};

        #pragma unroll
        for (int kp = 0; kp < K / 64; ++kp) {
            __syncthreads();
            #pragma unroll
            for (int it = 0; it < 8; ++it) {
                int idx = j + it * 256;
                int r = idx >> 4, kc = (idx & 15) << 2;
                int n = (nb << 7) + r, pn = (n & 3) * 128 + (n >> 2);
                float4 vw = *(const float4*)(W + (size_t)pn * K + kp * 64 + kc);
                *(f16x4*)&sW[r][kc] = (f16x4){(_Float16)vw.x, (_Float16)vw.y,
                                              (_Float16)vw.z, (_Float16)vw.w};
            }
            __syncthreads();
            #pragma unroll
            for (int kh = 0; kh < 2; ++kh) {
                const int kk = kh * 32 + q * 8;
                f16x8 a[4], bf[4];
                #pragma unroll
                for (int mt = 0; mt < 4; ++mt)
                    a[mt] = *(const f16x8*)&sA[wm * 64 + mt * 16 + n16][kp * 64 + kk];
                #pragma unroll
                for (int nt = 0; nt < 4; ++nt)
                    bf[nt] = *(const f16x8*)&sW[wn * 64 + nt * 16 + n16][kk];
                #pragma unroll
                for (int nt = 0; nt < 4; ++nt)
                    #pragma unroll
                    for (int mt = 0; mt < 4; ++mt)
                        acc[mt][nt] = MFMA16(a[mt], bf[nt], acc[mt][nt]);
            }
        }
        // epilogue: nt 0,1 -> grpA (e=0,1); nt 2,3 -> grpB. One b128 per
        // (mt, grp): 4 consecutive s x 2 e = 8 contiguous f16.
        const int N0 = (nb << 7) + wn * 64;
        const int nA = N0 + n16, nBc = N0 + 32 + n16;
        const int grpA = (nA >> 7) * 64 + ((nA >> 5) & 3) * 16 + (nA & 15);
        const int grpB = (nBc >> 7) * 64 + ((nBc >> 5) & 3) * 16 + (nBc & 15);
        #pragma unroll
        for (int mt = 0; mt < 4; ++mt) {
            int srow = (m0 + wm * 64 + mt * 16 + q * 4) & (T - 1);
            f16x8 pkA = {(_Float16)acc[mt][0][0], (_Float16)acc[mt][1][0],
                         (_Float16)acc[mt][0][1], (_Float16)acc[mt][1][1],
                         (_Float16)acc[mt][0][2], (_Float16)acc[mt][1][2],
                         (_Float16)acc[mt][0][3], (_Float16)acc[mt][1][3]};
            f16x8 pkB = {(_Float16)acc[mt][2][0], (_Float16)acc[mt][3][0],
                         (_Float16)acc[mt][2][1], (_Float16)acc[mt][3][1],
                         (_Float16)acc[mt][2][2], (_Float16)acc[mt][3][2],
                         (_Float16)acc[mt][2][3], (_Float16)acc[mt][3][3]};
            *(f16x8*)(O + bO + (size_t)grpA * 2048 + (size_t)srow * 2) = pkA;
            *(f16x8*)(O + bO + (size_t)grpB * 2048 + (size_t)srow * 2) = pkB;
        }
    }
}

// ---------------------------------------------------------------------------
// One-layer LSTM scan: 256 blocks (1 batch each -> all CUs), 256 thr
// (4 waves = 1/SIMD). Wave v owns gate'-cols [128v,128v+128) = 8 N-tiles;
// h replicated over all 16 M-rows so every acc element equals the col value.
// Lane (q,l15) owns tiles {2q,2q+1}: gate extraction = 3-cndmask q-tree on
// acc[2q][0]/acc[2q+1][0]. Quad (q,u) lanes gg=0..3 hold gates i,f,g,o of
// hu=32v+4j+u -> own-gate activation + quad-DPP (round-1-verified). tanh and
// h/hist writes only in gg<2 lanes. Weights: 128 VGPR/lane (whh only).
// ---------------------------------------------------------------------------
__global__ __launch_bounds__(256, 1)
void lstm_scan(const _Float16* __restrict__ xg, const float* __restrict__ whh,
               const float* __restrict__ bias, const float* __restrict__ h0g,
               _Float16* hist, const float* __restrict__ fcw,
               const float* __restrict__ fcb, float* __restrict__ out, int dofc)
{
    __shared__ _Float16 __align__(16) hb[2][128];
    __shared__ float lds_r[128];

    const int b = blockIdx.x;
    const int t = threadIdx.x;          // 0..255
    const int lane = t & 63, v = t >> 6;
    const int l15 = lane & 15, q = lane >> 4;
    const int u = l15 >> 2, gg = l15 & 3;

    // B-fragments: wf[j][kt] = whh[gate' col n][k], n = 128v+16j+l15,
    // k = 32kt + q*8 + jj
    f16x8 wf[8][4];
    #pragma unroll
    for (int jj = 0; jj < 8; ++jj) {
        const int n  = 128 * v + 16 * jj + l15;
        const int pn = (n & 3) * 128 + (n >> 2);
        const float* wr = whh + (size_t)pn * H;
        #pragma unroll
        for (int kt = 0; kt < 4; ++kt)
            wf[jj][kt] = cvt8(wr + 32 * kt + q * 8);
    }
    const int huA = 32 * v + 8 * q + u;          // hu of tile 2q
    const int huB = huA + 4;                     // hu of tile 2q+1
    const float bjA = bias[gg * 128 + huA];
    const float bjB = bias[gg * 128 + huB];

    const bool  isg = (gg == 2);
    const float nsc = isg ? -2.0f : -1.0f;
    const float va  = isg ?  2.0f :  1.0f;
    const float vb  = isg ? -1.0f :  0.0f;
    const bool  sq0 = (q & 1) != 0;
    const bool  sq1 = (q & 2) != 0;
    const bool  wlane = gg < 2;
    const int   hu_own = wlane ? (gg ? huB : huA) : huA;   // valid if wlane

    if (t < H) hb[0][t] = (_Float16)h0g[(size_t)b * H + t];

    float cA = 0.f, cB = 0.f, hOwn = 0.f;

    const _Float16* xgp = xg + (size_t)b * TG4 + (size_t)(v * 64 + q * 16 + l15) * 2048;
    f16x8 xr0 = *(const f16x8*)(xgp + 0);    // steps 0..3
    f16x8 xr1 = *(const f16x8*)(xgp + 8);    // steps 4..7

    _Float16* hp = hist ? hist + (size_t)b * TG4 + (size_t)(hu_own >> 1) * 2048 + (hu_own & 1)
                        : (_Float16*)0;

    __syncthreads();

    const f32x4 z = (f32x4){0.f, 0.f, 0.f, 0.f};

    for (int sb = 0; sb < T; sb += 8) {
        #pragma unroll
        for (int ss = 0; ss < 8; ++ss) {
            const int s = sb + ss;
            const int p = s & 1;

            f16x8 xcur = (ss < 4) ? xr0 : xr1;
            float xA = (float)xcur[(ss & 3) * 2];
            float xB = (float)xcur[(ss & 3) * 2 + 1];

            f16x8 af[4];
            #pragma unroll
            for (int kt = 0; kt < 4; ++kt)
                af[kt] = *(const f16x8*)(&hb[p][32 * kt + q * 8]);

            f32x4 a[8];
            #pragma unroll
            for (int jj = 0; jj < 8; ++jj)
                a[jj] = MFMA16(af[0], wf[jj][0], z);
            #pragma unroll
            for (int kt = 1; kt < 4; ++kt)
                #pragma unroll
                for (int jj = 0; jj < 8; ++jj)
                    a[jj] = MFMA16(af[kt], wf[jj][kt], a[jj]);

            // own 2 cols: tiles 2q (e=0) and 2q+1 (e=1); all acc elems equal
            float gA = (sq0 ? (sq1 ? a[6][0] : a[2][0]) : (sq1 ? a[4][0] : a[0][0]))
                       + xA + bjA;
            float gB = (sq0 ? (sq1 ? a[7][0] : a[3][0]) : (sq1 ? a[5][0] : a[1][0]))
                       + xB + bjB;

            // ring reload (distance 5+ steps)
            if (ss == 3) { int i0 = sb + 8;  if (i0 > T - 4) i0 = T - 4; xr0 = *(const f16x8*)(xgp + (size_t)i0 * 2); }
            if (ss == 7) { int i1 = sb + 12; if (i1 > T - 4) i1 = T - 4; xr1 = *(const f16x8*)(xgp + (size_t)i1 * 2); }

            float uA  = 1.0f / (1.0f + __expf(nsc * gA));
            float vlA = fmaf(uA, va, vb);
            float uB  = 1.0f / (1.0f + __expf(nsc * gB));
            float vlB = fmaf(uB, va, vb);

            float niA = DPPQ(vlA, 0x00), nfA = DPPQ(vlA, 0x55);
            float ngA = DPPQ(vlA, 0xAA), noA = DPPQ(vlA, 0xFF);
            float niB = DPPQ(vlB, 0x00), nfB = DPPQ(vlB, 0x55);
            float ngB = DPPQ(vlB, 0xAA), noB = DPPQ(vlB, 0xFF);

            cA = nfA * cA + niA * ngA;
            cB = nfB * cB + niB * ngB;

            if (wlane) {
                float cs = gg ? cB : cA;
                float ns = gg ? noB : noA;
                float h  = ns * tanhf_(cs);
                hOwn = h;
                hb[p ^ 1][hu_own] = (_Float16)h;
                if (hp) hp[(size_t)s * 2] = (_Float16)h;
            }

            wg_barrier();
        }
    }

    if (dofc) {
        if (wlane) lds_r[hu_own] = hOwn * fcw[hu_own];
        __syncthreads();
        if (t == 0) {
            float s_ = fcb[0];
            for (int k = 0; k < H; ++k) s_ += lds_r[k];
            out[b] = s_;
        }
    }
}

extern "C" void kernel_launch(void* const* d_in, const int* in_sizes, int n_in,
                              void* d_out, int out_size, void* d_ws, size_t ws_size,
                              hipStream_t stream)
{
    const float* x    = (const float*)d_in[0];
    const float* h0   = (const float*)d_in[1];
    const float* wih0 = (const float*)d_in[2];
    const float* whh0 = (const float*)d_in[3];
    const float* b0   = (const float*)d_in[4];
    const float* wih1 = (const float*)d_in[5];
    const float* whh1 = (const float*)d_in[6];
    const float* b1   = (const float*)d_in[7];
    const float* fcw  = (const float*)d_in[8];
    const float* fcb  = (const float*)d_in[9];
    float* out = (float*)d_out;

    _Float16* xg = (_Float16*)d_ws;   // [NB][256 grp][T][2] f16 = 256 MiB

    // 1) xg0 = wih0 @ x  (packed layout)
    gemm_pp<64, 0><<<NBT / 128, 256, 0, stream>>>(x, wih0, xg);
    // 2) layer-0 scan; h0-history overlaid into xg grps 0..63 (rate-matched)
    lstm_scan<<<NB, 256, 0, stream>>>(xg, whh0, b0, h0, xg,
                                      nullptr, nullptr, nullptr, 0);
    // 3) xg1 = wih1 @ h0hist (in place, block-local s-ranges, race-free)
    gemm_pp<128, 1><<<NBT / 128, 256, 0, stream>>>(xg, wih1, xg);
    // 4) layer-1 scan + fused FC
    lstm_scan<<<NB, 256, 0, stream>>>(xg, whh1, b1, h0 + (size_t)NB * H,
                                      nullptr, fcw, fcb, out, 1);
}

// Round 9
// 1237.072 us; speedup vs baseline: 3.4871x; 1.0346x over previous
//
#include <hip/hip_runtime.h>
#include <math.h>

#define NB  256
#define T   1024
#define DIN 64
#define H   128
#define G4  512
#define NBT (NB * T)
#define TG4 (T * G4)      // elems per batch in packed xg (1 MiB / 2B)

typedef __attribute__((ext_vector_type(4))) float    f32x4;
typedef __attribute__((ext_vector_type(8))) _Float16 f16x8;
typedef __attribute__((ext_vector_type(4))) _Float16 f16x4;
typedef __attribute__((ext_vector_type(2))) _Float16 f16x2;

#define DPPQ(v, CTRL) __int_as_float(__builtin_amdgcn_update_dpp(0, __float_as_int(v), (CTRL), 0xf, 0xf, true))
#define MFMA16(A, B, C) __builtin_amdgcn_mfma_f32_16x16x32_f16((A), (B), (C), 0, 0, 0)
#define PN(n) ((((n) & 3) * 128) + ((n) >> 2))

__device__ __forceinline__ float tanhf_(float x) { return 2.0f / (1.0f + __expf(-2.0f * x)) - 1.0f; }

__device__ __forceinline__ void wg_barrier() {
    asm volatile("s_waitcnt lgkmcnt(0)" ::: "memory");
    __builtin_amdgcn_s_barrier();
}

__device__ __forceinline__ f16x8 cvt8(const float* p) {
    float4 v0 = *(const float4*)p;
    float4 v1 = *(const float4*)(p + 4);
    return (f16x8){(_Float16)v0.x, (_Float16)v0.y, (_Float16)v0.z, (_Float16)v0.w,
                   (_Float16)v1.x, (_Float16)v1.y, (_Float16)v1.z, (_Float16)v1.w};
}

// ---------------------------------------------------------------------------
// xg layout: addr(b, grp, s, e) = b*TG4 + grp*2048 + s*2 + e, where gate' col
// n -> grp = (n>>7)*64 + ((n>>5)&3)*16 + (n&15), e = (n>>4)&1.
// BIAS IS FOLDED INTO xg at the epilogue (f32 add before f16 store).
// hist (h0 history) overlays xg grps 0..63 (rate-matched, round-8-verified).
// ---------------------------------------------------------------------------
template<int K, int AH>
__global__ __launch_bounds__(256, 2)
void gemm_pp(const void* __restrict__ A, const float* __restrict__ W,
             const float* __restrict__ bias, _Float16* __restrict__ O)
{
    __shared__ _Float16 __align__(16) sA[128][136];
    __shared__ _Float16 __align__(16) sW[128][72];

    const int m0 = blockIdx.x << 7;
    const int j = threadIdx.x;
    const int lane = j & 63, wv = j >> 6;
    const int wm = wv >> 1, wn = wv & 1;
    const int q = lane >> 4, n16 = lane & 15;
    const int bb = m0 >> 10, s0 = m0 & (T - 1);
    const size_t bO = (size_t)bb * TG4;

    if constexpr (AH) {
        // hist pair layout: A[s][k] = buf[bO + (k>>1)*2048 + s*2 + (k&1)]
        const _Float16* Ah = (const _Float16*)A;
        #pragma unroll
        for (int it = 0; it < 8; ++it) {
            int idx = j + it * 256;              // 64 kp x 32 sblk
            int kp = idx & 63, sblk = idx >> 6;
            f16x8 xv8 = *(const f16x8*)(Ah + bO + (size_t)kp * 2048
                                        + (size_t)(s0 + sblk * 4) * 2);
            #pragma unroll
            for (int d = 0; d < 4; ++d)
                *(f16x2*)&sA[sblk * 4 + d][2 * kp] = (f16x2){xv8[2 * d], xv8[2 * d + 1]};
        }
    } else {
        const float* Af = (const float*)A;
        #pragma unroll
        for (int it = 0; it < 8; ++it) {         // 128 rows x 16 float4 chunks
            int idx = j + it * 256;
            int r = idx >> 4, kc = (idx & 15) << 2;
            float4 va = *(const float4*)(Af + (size_t)(m0 + r) * K + kc);
            *(f16x4*)&sA[r][kc] = (f16x4){(_Float16)va.x, (_Float16)va.y,
                                          (_Float16)va.z, (_Float16)va.w};
        }
    }

    for (int nb = 0; nb < 4; ++nb) {
        f32x4 acc[4][4];
        #pragma unroll
        for (int a = 0; a < 4; ++a)
            #pragma unroll
            for (int bq = 0; bq < 4; ++bq) acc[a][bq] = (f32x4){0.f, 0.f, 0.f, 0.f};

        #pragma unroll
        for (int kp = 0; kp < K / 64; ++kp) {
            __syncthreads();
            #pragma unroll
            for (int it = 0; it < 8; ++it) {
                int idx = j + it * 256;
                int r = idx >> 4, kc = (idx & 15) << 2;
                int n = (nb << 7) + r, pn = PN(n);
                float4 vw = *(const float4*)(W + (size_t)pn * K + kp * 64 + kc);
                *(f16x4*)&sW[r][kc] = (f16x4){(_Float16)vw.x, (_Float16)vw.y,
                                              (_Float16)vw.z, (_Float16)vw.w};
            }
            __syncthreads();
            #pragma unroll
            for (int kh = 0; kh < 2; ++kh) {
                const int kk = kh * 32 + q * 8;
                f16x8 a[4], bf[4];
                #pragma unroll
                for (int mt = 0; mt < 4; ++mt)
                    a[mt] = *(const f16x8*)&sA[wm * 64 + mt * 16 + n16][kp * 64 + kk];
                #pragma unroll
                for (int nt = 0; nt < 4; ++nt)
                    bf[nt] = *(const f16x8*)&sW[wn * 64 + nt * 16 + n16][kk];
                #pragma unroll
                for (int nt = 0; nt < 4; ++nt)
                    #pragma unroll
                    for (int mt = 0; mt < 4; ++mt)
                        acc[mt][nt] = MFMA16(a[mt], bf[nt], acc[mt][nt]);
            }
        }
        // epilogue: nt 0,1 -> grpA (e=0,1); nt 2,3 -> grpB; + bias fold.
        const int N0 = (nb << 7) + wn * 64;
        const int nA = N0 + n16, nBc = N0 + 32 + n16;
        const int grpA = (nA >> 7) * 64 + ((nA >> 5) & 3) * 16 + (nA & 15);
        const int grpB = (nBc >> 7) * 64 + ((nBc >> 5) & 3) * 16 + (nBc & 15);
        const float biA0 = bias[PN(N0 + n16)];
        const float biA1 = bias[PN(N0 + 16 + n16)];
        const float biB0 = bias[PN(N0 + 32 + n16)];
        const float biB1 = bias[PN(N0 + 48 + n16)];
        #pragma unroll
        for (int mt = 0; mt < 4; ++mt) {
            int srow = (m0 + wm * 64 + mt * 16 + q * 4) & (T - 1);
            f16x8 pkA = {(_Float16)(acc[mt][0][0] + biA0), (_Float16)(acc[mt][1][0] + biA1),
                         (_Float16)(acc[mt][0][1] + biA0), (_Float16)(acc[mt][1][1] + biA1),
                         (_Float16)(acc[mt][0][2] + biA0), (_Float16)(acc[mt][1][2] + biA1),
                         (_Float16)(acc[mt][0][3] + biA0), (_Float16)(acc[mt][1][3] + biA1)};
            f16x8 pkB = {(_Float16)(acc[mt][2][0] + biB0), (_Float16)(acc[mt][3][0] + biB1),
                         (_Float16)(acc[mt][2][1] + biB0), (_Float16)(acc[mt][3][1] + biB1),
                         (_Float16)(acc[mt][2][2] + biB0), (_Float16)(acc[mt][3][2] + biB1),
                         (_Float16)(acc[mt][2][3] + biB0), (_Float16)(acc[mt][3][3] + biB1)};
            *(f16x8*)(O + bO + (size_t)grpA * 2048 + (size_t)srow * 2) = pkA;
            *(f16x8*)(O + bO + (size_t)grpB * 2048 + (size_t)srow * 2) = pkB;
        }
    }
}

// ---------------------------------------------------------------------------
// One-layer LSTM scan: 256 blocks (1 batch each -> all CUs), 512 thr
// (8 waves = 2/SIMD -> VALU of one wave overlaps MFMA of the other).
// Lane t owns gate' col n == t (gate = t&3, hu = t>>2 -- round-1-verified
// quad-DPP layout). Wave v owns cols [64v,64v+64) = 4 N-tiles = 16 MFMA;
// h replicated over all 16 M-rows so every acc element equals the col value;
// own value = 3-cndmask q-select. Weights: 64 VGPR/lane (whh only).
// Bias pre-folded into xg. tanh + h/hist write only in gate-0 lanes.
// ---------------------------------------------------------------------------
__global__ __launch_bounds__(512, 1)
void lstm_scan(const _Float16* __restrict__ xg, const float* __restrict__ whh,
               const float* __restrict__ h0g, _Float16* hist,
               const float* __restrict__ fcw, const float* __restrict__ fcb,
               float* __restrict__ out, int dofc)
{
    __shared__ _Float16 __align__(16) hb[2][128];
    __shared__ float lds_r[128];

    const int b = blockIdx.x;
    const int t = threadIdx.x;          // 0..511; col n == t
    const int lane = t & 63, v = t >> 6;
    const int l15 = lane & 15, q = lane >> 4;
    const int gg = t & 3, hu = t >> 2;

    // B-fragments: wf[j][kt] = whh[gate' col n][k], n = 64v+16j+l15,
    // k = 32kt + q*8 + jj
    f16x8 wf[4][4];
    #pragma unroll
    for (int jj = 0; jj < 4; ++jj) {
        const int n  = 64 * v + 16 * jj + l15;
        const int pn = PN(n);
        const float* wr = whh + (size_t)pn * H;
        #pragma unroll
        for (int kt = 0; kt < 4; ++kt)
            wf[jj][kt] = cvt8(wr + 32 * kt + q * 8);
    }

    const bool  isg = (gg == 2);
    const float nsc = isg ? -2.0f : -1.0f;
    const float va  = isg ?  2.0f :  1.0f;
    const float vb  = isg ? -1.0f :  0.0f;
    const bool  s4  = (lane & 16) != 0;
    const bool  s5  = (lane & 32) != 0;
    const bool  wlane = (gg == 0);

    if (t < H) hb[0][t] = (_Float16)h0g[(size_t)b * H + t];

    float c = 0.f, hOwn = 0.f;

    // xg plane for col t: grp/e from the packed layout
    const int grp = (t >> 7) * 64 + ((t >> 5) & 3) * 16 + (t & 15);
    const int e   = (t >> 4) & 1;
    const _Float16* xgp = xg + (size_t)b * TG4 + (size_t)grp * 2048;
    f16x8 xr0 = *(const f16x8*)(xgp + 0);    // steps 0..3 (pairs e=0,1)
    f16x8 xr1 = *(const f16x8*)(xgp + 8);    // steps 4..7

    _Float16* hp = (hist && wlane)
        ? hist + (size_t)b * TG4 + (size_t)(hu >> 1) * 2048 + (hu & 1)
        : (_Float16*)0;

    __syncthreads();

    const f32x4 z = (f32x4){0.f, 0.f, 0.f, 0.f};

    for (int sb = 0; sb < T; sb += 8) {
        #pragma unroll
        for (int ss = 0; ss < 8; ++ss) {
            const int s = sb + ss;
            const int p = s & 1;

            // own xg value: compile-time extracts + uniform cndmask on e
            f16x8 xcur = (ss < 4) ? xr0 : xr1;
            const int k2 = (ss & 3) * 2;
            float xv = e ? (float)xcur[k2 + 1] : (float)xcur[k2];

            f16x8 af[4];
            #pragma unroll
            for (int kt = 0; kt < 4; ++kt)
                af[kt] = *(const f16x8*)(&hb[p][32 * kt + q * 8]);

            f32x4 a0 = MFMA16(af[0], wf[0][0], z);
            f32x4 a1 = MFMA16(af[0], wf[1][0], z);
            f32x4 a2 = MFMA16(af[0], wf[2][0], z);
            f32x4 a3 = MFMA16(af[0], wf[3][0], z);
            #pragma unroll
            for (int kt = 1; kt < 4; ++kt) {
                a0 = MFMA16(af[kt], wf[0][kt], a0);
                a1 = MFMA16(af[kt], wf[1][kt], a1);
                a2 = MFMA16(af[kt], wf[2][kt], a2);
                a3 = MFMA16(af[kt], wf[3][kt], a3);
            }

            // ring reload (distance ~5 steps)
            if (ss == 3) { int i0 = sb + 8;  if (i0 > T - 4) i0 = T - 4; xr0 = *(const f16x8*)(xgp + (size_t)i0 * 2); }
            if (ss == 7) { int i1 = sb + 12; if (i1 > T - 4) i1 = T - 4; xr1 = *(const f16x8*)(xgp + (size_t)i1 * 2); }

            // own col value: tile q, any acc row (h replicated over M)
            float own = s5 ? (s4 ? a3[0] : a2[0]) : (s4 ? a1[0] : a0[0]);
            float g = own + xv;                  // bias pre-folded into xg

            float uu = 1.0f / (1.0f + __expf(nsc * g));
            float vl = fmaf(uu, va, vb);

            float ni = DPPQ(vl, 0x00), nf = DPPQ(vl, 0x55);
            float ng = DPPQ(vl, 0xAA), no = DPPQ(vl, 0xFF);
            c = nf * c + ni * ng;                // quad-redundant c

            if (wlane) {
                float h = no * tanhf_(c);
                hOwn = h;
                hb[p ^ 1][hu] = (_Float16)h;
                if (hp) hp[(size_t)s * 2] = (_Float16)h;
            }

            wg_barrier();
        }
    }

    if (dofc) {
        if (wlane) lds_r[hu] = hOwn * fcw[hu];
        __syncthreads();
        if (t == 0) {
            float s_ = fcb[0];
            for (int k = 0; k < H; ++k) s_ += lds_r[k];
            out[b] = s_;
        }
    }
}

extern "C" void kernel_launch(void* const* d_in, const int* in_sizes, int n_in,
                              void* d_out, int out_size, void* d_ws, size_t ws_size,
                              hipStream_t stream)
{
    const float* x    = (const float*)d_in[0];
    const float* h0   = (const float*)d_in[1];
    const float* wih0 = (const float*)d_in[2];
    const float* whh0 = (const float*)d_in[3];
    const float* b0   = (const float*)d_in[4];
    const float* wih1 = (const float*)d_in[5];
    const float* whh1 = (const float*)d_in[6];
    const float* b1   = (const float*)d_in[7];
    const float* fcw  = (const float*)d_in[8];
    const float* fcb  = (const float*)d_in[9];
    float* out = (float*)d_out;

    _Float16* xg = (_Float16*)d_ws;   // [NB][256 grp][T][2] f16 = 256 MiB

    // 1) xg0 = wih0 @ x + b0  (packed layout, bias folded)
    gemm_pp<64, 0><<<NBT / 128, 256, 0, stream>>>(x, wih0, b0, xg);
    // 2) layer-0 scan; h0-history overlaid into xg grps 0..63 (rate-matched)
    lstm_scan<<<NB, 512, 0, stream>>>(xg, whh0, h0, xg,
                                      nullptr, nullptr, nullptr, 0);
    // 3) xg1 = wih1 @ h0hist + b1 (in place, block-local s-ranges, race-free)
    gemm_pp<128, 1><<<NBT / 128, 256, 0, stream>>>(xg, wih1, b1, xg);
    // 4) layer-1 scan + fused FC
    lstm_scan<<<NB, 512, 0, stream>>>(xg, whh1, h0 + (size_t)NB * H,
                                      nullptr, fcw, fcb, out, 1);
}